// Round 1
// baseline (1019.997 us; speedup 1.0000x reference)
//
#include <hip/hip_runtime.h>
#include <hip/hip_bf16.h>
#include <math.h>

#define B 512
#define T 64
#define NL 32
#define LAT 64
#define HID 128
#define DIN 65
#define G3 384
#define FSCALE 365.0f
#define MAXGRID 128

// ws layout (float index)
#define WS_MIN   0   // int
#define WS_MAX   1   // int
#define WS_NIT   2   // int
#define WS_KL    3
#define WS_RE    4
#define WS_NO    5
#define WS_GRID  8                 // MAXGRID floats
#define WS_Z0    (WS_GRID + MAXGRID)
#define WS_YS    (WS_Z0 + B*LAT)   // MAXGRID * B * LAT floats

static __device__ __forceinline__ unsigned bf16_rne(float f){
    union { float f; unsigned u; } v; v.f = f;
    unsigned r = v.u + 0x7fffu + ((v.u >> 16) & 1u);
    return r & 0xffff0000u ? (r >> 16) : (r >> 16);
}
static __device__ __forceinline__ float bf_lo(unsigned p){
    union { unsigned u; float f; } v; v.u = p << 16; return v.f;
}
static __device__ __forceinline__ float bf_hi(unsigned p){
    union { unsigned u; float f; } v; v.u = p & 0xffff0000u; return v.f;
}
static __device__ __forceinline__ float sigmoidf_(float x){ return 1.0f/(1.0f+expf(-x)); }

// ---------------- kernel 1: init accumulators + min/max of timepoints ----------------
__global__ void k_init(const int* __restrict__ tp, float* wsf){
    int* wsi = (int*)wsf;
    __shared__ int smin[256], smax[256];
    int tid = threadIdx.x;
    int mn = 2147483647, mx = -2147483647-1;
    for (int i = tid; i < B*T; i += 256){ int v = tp[i]; mn = min(mn,v); mx = max(mx,v); }
    smin[tid]=mn; smax[tid]=mx; __syncthreads();
    for (int s=128; s>0; s>>=1){
        if (tid<s){ smin[tid]=min(smin[tid],smin[tid+s]); smax[tid]=max(smax[tid],smax[tid+s]); }
        __syncthreads();
    }
    if (tid==0){
        wsi[WS_MIN]=smin[0]; wsi[WS_MAX]=smax[0];
        wsf[WS_KL]=0.f; wsf[WS_RE]=0.f; wsf[WS_NO]=0.f;
    }
}

// ---------------- kernel 2: build integration grid (f64 to match numpy) ----------------
__global__ void k_grid(float* wsf){
    int* wsi=(int*)wsf;
    float t0f = (float)wsi[WS_MIN] / FSCALE;
    float t1f = (float)wsi[WS_MAX] / FSCALE;
    double t0d = (double)t0f, t1d = (double)t1f;
    int nit = (int)ceil((t1d-t0d)/0.05 + 1.0);
    if (nit < 1) nit = 1;
    if (nit > MAXGRID) nit = MAXGRID;
    if (threadIdx.x==0) wsi[WS_NIT] = nit;
    int k = threadIdx.x;
    if (k < nit){
        double g = (double)k * 0.05 + t0d;
        if (k == nit-1 && g > t1d) g = t1d;
        wsf[WS_GRID + k] = (float)g;
    }
}

// ---------------- kernel 3: GRU encoder (1 row/block, weights bf16 in VGPRs) ----------------
__global__ __launch_bounds__(384) void k_gru(
    const float* __restrict__ obs, const float* __restrict__ eps,
    const float* __restrict__ Wih, const float* __restrict__ Whh,
    const float* __restrict__ bih, const float* __restrict__ bhh,
    const float* __restrict__ Wmu, const float* __restrict__ bmu,
    const float* __restrict__ Wlv, const float* __restrict__ blv,
    const int* __restrict__ maskI, const int* __restrict__ tp,
    float* wsf)
{
    int b = blockIdx.x, j = threadIdx.x;
    __shared__ float xs[72];
    __shared__ float hs[HID];
    __shared__ float gbi[G3], gbh[G3];

    unsigned wih[33], whh[64];
    #pragma unroll
    for (int i=0;i<33;++i){
        float lo = Wih[(2*i)*G3 + j];
        float hi = (2*i+1 < DIN) ? Wih[(2*i+1)*G3 + j] : 0.f;
        wih[i] = (bf16_rne(lo)) | (bf16_rne(hi)<<16);
    }
    #pragma unroll
    for (int i=0;i<64;++i){
        float lo = Whh[(2*i)*G3 + j];
        float hi = Whh[(2*i+1)*G3 + j];
        whh[i] = (bf16_rne(lo)) | (bf16_rne(hi)<<16);
    }
    float bi = bih[j], bh = bhh[j];
    if (j < HID) hs[j] = 0.f;
    if (j >= 65 && j < 72) xs[j] = 0.f;
    __syncthreads();

    for (int s=0;s<T;++s){
        int t = T-1-s;
        if (j < NL){
            float mv = (float)maskI[(b*T + t)*NL + j];
            xs[j] = obs[(b*T + t)*NL + j] * mv;
            xs[NL + j] = mv;
        } else if (j == 64){
            float d = 0.f;
            if (t > 0) d = (float)(tp[b*T+t] - tp[b*T+t-1]);
            xs[64] = d;
        }
        __syncthreads();
        float gi = bi, gh = bh;
        #pragma unroll
        for (int i=0;i<33;++i){
            unsigned p = wih[i];
            gi = fmaf(xs[2*i],   bf_lo(p), gi);
            gi = fmaf(xs[2*i+1], bf_hi(p), gi);
        }
        #pragma unroll
        for (int i=0;i<64;++i){
            unsigned p = whh[i];
            gh = fmaf(hs[2*i],   bf_lo(p), gh);
            gh = fmaf(hs[2*i+1], bf_hi(p), gh);
        }
        gbi[j] = gi; gbh[j] = gh;
        __syncthreads();
        if (j < HID){
            float r  = sigmoidf_(gbi[j] + gbh[j]);
            float zg = sigmoidf_(gbi[j+HID] + gbh[j+HID]);
            float n  = tanhf(gbi[j+2*HID] + r*gbh[j+2*HID]);
            hs[j] = (1.f - zg)*n + zg*hs[j];
        }
        __syncthreads();
    }

    if (j < LAT){
        float mu = bmu[j], lv = blv[j];
        #pragma unroll 8
        for (int k=0;k<HID;++k){
            mu = fmaf(hs[k], Wmu[k*LAT + j], mu);
            lv = fmaf(hs[k], Wlv[k*LAT + j], lv);
        }
        float z0 = mu + eps[b*LAT + j]*expf(0.5f*lv);
        wsf[WS_Z0 + b*LAT + j] = z0;
        wsf[WS_YS + (size_t)b*LAT + j] = z0;  // ys[0]
        float term = 1.f + lv - mu*mu - expf(lv);
        #pragma unroll
        for (int off=32; off>0; off>>=1) term += __shfl_down(term, off);
        if (j==0) atomicAdd(&wsf[WS_KL], term);
    }
}

// ---------------- kernel 4: RK4 ODE integration (1 row/block, W in VGPRs) ----------------
__global__ __launch_bounds__(256) void k_ode(
    const float* __restrict__ W1, const float* __restrict__ b1,
    const float* __restrict__ W2, const float* __restrict__ b2,
    const float* __restrict__ W3, const float* __restrict__ b3,
    float* wsf)
{
    int b = blockIdx.x;
    int tid = threadIdx.x;
    int wid = tid >> 6, lane = tid & 63;
    int l5 = lane & 31, kh = lane >> 5;
    int j  = wid*32 + l5;          // hidden column 0..127
    int l3 = (wid & 1)*32 + l5;    // stage-3 output 0..63
    int kq = (wid >> 1)*2 + kh;    // stage-3 k-quarter 0..3
    const int* wsi = (const int*)wsf;
    int nit = wsi[WS_NIT];

    __shared__ float zin[64], h1s[128], h2s[128], part[2][64], b3s[64], gls[MAXGRID];

    float w1r[32], w2r[64], w3r[32];
    #pragma unroll
    for (int k=0;k<32;++k) w1r[k] = W1[(kh*32+k)*HID + j];
    #pragma unroll
    for (int k=0;k<64;++k) w2r[k] = W2[(kh*64+k)*HID + j];
    #pragma unroll
    for (int k=0;k<32;++k) w3r[k] = W3[(kq*32+k)*LAT + l3];
    float b1j = b1[j], b2j = b2[j];
    if (tid < 64) b3s[tid] = b3[tid];
    for (int k=tid; k<MAXGRID; k+=256) gls[k] = wsf[WS_GRID+k];
    float yreg = 0.f, facc = 0.f;
    if (tid < 64){
        yreg = wsf[WS_Z0 + b*LAT + tid];
        zin[tid] = yreg;
    }
    __syncthreads();

    for (int i=0; i<nit-1; ++i){
        float h = gls[i+1]-gls[i];
        #pragma unroll
        for (int sub=0; sub<4; ++sub){
            // stage 1: 64 -> 128, tanh
            float acc = 0.f;
            {
                const float* zp = &zin[kh*32];
                #pragma unroll
                for (int k=0;k<32;++k) acc = fmaf(zp[k], w1r[k], acc);
            }
            acc += __shfl_xor(acc, 32);
            float h1 = tanhf(b1j + acc);
            if (kh==0) h1s[j] = h1;
            __syncthreads();
            // stage 2: 128 -> 128, tanh
            acc = 0.f;
            {
                const float* hp = &h1s[kh*64];
                #pragma unroll
                for (int k=0;k<64;++k) acc = fmaf(hp[k], w2r[k], acc);
            }
            acc += __shfl_xor(acc, 32);
            float h2 = tanhf(b2j + acc);
            if (kh==0) h2s[j] = h2;
            __syncthreads();
            // stage 3: 128 -> 64
            acc = 0.f;
            {
                const float* qp = &h2s[kq*32];
                #pragma unroll
                for (int k=0;k<32;++k) acc = fmaf(qp[k], w3r[k], acc);
            }
            acc += __shfl_xor(acc, 32);
            if (kh==0) part[wid>>1][l3] = acc;
            __syncthreads();
            if (tid < 64){
                float f = b3s[tid] + part[0][tid] + part[1][tid];
                if (sub==0){ facc = f;        zin[tid] = fmaf(0.5f*h, f, yreg); }
                else if (sub==1){ facc += 2.f*f; zin[tid] = fmaf(0.5f*h, f, yreg); }
                else if (sub==2){ facc += 2.f*f; zin[tid] = fmaf(h, f, yreg); }
                else {
                    facc += f;
                    yreg = yreg + (h/6.0f)*facc;
                    zin[tid] = yreg;
                    wsf[WS_YS + ((size_t)(i+1)*B + b)*LAT + tid] = yreg;
                }
            }
            __syncthreads();
        }
    }
}

// ---------------- kernel 5: interpolation + decoder + masked MSE / n_obs ----------------
__global__ __launch_bounds__(128) void k_recon(
    const float* __restrict__ obs, const int* __restrict__ maskI,
    const int* __restrict__ tp, const int* __restrict__ seq,
    const float* __restrict__ Wo1, const float* __restrict__ bo1,
    const float* __restrict__ Wo2, const float* __restrict__ bo2,
    float* wsf)
{
    int b = blockIdx.x, tid = threadIdx.x;
    __shared__ float wo1[LAT*HID];
    __shared__ float wo2[HID*NL];
    __shared__ float bo1s[HID];
    __shared__ float bo2s[NL];
    __shared__ float gls[MAXGRID];
    __shared__ float zbt[64], hb[HID], p2[4][NL], red[32];
    const int* wsi=(const int*)wsf;
    int nit = wsi[WS_NIT];
    for (int i=tid;i<LAT*HID;i+=128) wo1[i]=Wo1[i];
    for (int i=tid;i<HID*NL;i+=128) wo2[i]=Wo2[i];
    if (tid<HID) bo1s[tid]=bo1[tid];
    if (tid<NL)  bo2s[tid]=bo2[tid];
    for (int i=tid;i<MAXGRID;i+=128) gls[i]=wsf[WS_GRID+i];
    int sl = seq[b];
    float esum=0.f, ncnt=0.f;
    __syncthreads();
    for (int t=0;t<T;++t){
        float tq = (float)tp[b*T+t] / FSCALE;
        int lo=0, hi=nit;
        while (lo<hi){ int mid=(lo+hi)>>1; if (gls[mid]<=tq) lo=mid+1; else hi=mid; }
        int k = lo-1; if (k<0) k=0; if (nit>=2 && k>nit-2) k=nit-2; if (nit<2) k=0;
        float w=0.f;
        if (nit>=2){ float tl=gls[k], tr=gls[k+1]; float den=(tr-tl==0.f)?1.f:(tr-tl); w=(tq-tl)/den; }
        if (tid<LAT){
            size_t o0 = (size_t)WS_YS + ((size_t)k*B + b)*LAT + tid;
            float zl = wsf[o0]*(1.f-w) + ((nit>=2)? wsf[o0 + (size_t)B*LAT]*w : 0.f);
            zbt[tid]=zl;
        }
        __syncthreads();
        float hj = bo1s[tid];
        #pragma unroll 8
        for (int l=0;l<LAT;++l) hj = fmaf(zbt[l], wo1[l*HID+tid], hj);
        hj = fmaxf(hj, 0.f);
        hb[tid] = hj;
        __syncthreads();
        {
            int o = tid & 31, q = tid >> 5;
            float ps = 0.f;
            #pragma unroll 8
            for (int kk=0;kk<32;++kk) ps = fmaf(hb[q*32+kk], wo2[(q*32+kk)*NL + o], ps);
            p2[q][o] = ps;
        }
        __syncthreads();
        if (tid < NL){
            float xh = bo2s[tid] + p2[0][tid]+p2[1][tid]+p2[2][tid]+p2[3][tid];
            float mv = (float)maskI[(b*T+t)*NL+tid] * ((t<sl)?1.f:0.f);
            float d = xh - obs[(b*T+t)*NL+tid];
            esum = fmaf(mv*d, d, esum);
            ncnt += mv;
        }
        __syncthreads();
    }
    if (tid<NL) red[tid]=esum;
    __syncthreads();
    if (tid==0){ float s=0.f; for(int i=0;i<32;++i) s+=red[i]; atomicAdd(&wsf[WS_RE], s); }
    __syncthreads();
    if (tid<NL) red[tid]=ncnt;
    __syncthreads();
    if (tid==0){ float s=0.f; for(int i=0;i<32;++i) s+=red[i]; atomicAdd(&wsf[WS_NO], s); }
}

// ---------------- kernel 6: z_eval + survival head ----------------
__global__ __launch_bounds__(128) void k_surv(
    const float* __restrict__ age, const int* __restrict__ tp, const int* __restrict__ seq,
    const float* __restrict__ Ws1, const float* __restrict__ bs1,
    const float* __restrict__ Ws2, const float* __restrict__ bs2,
    float* wsf, float* out)
{
    int b=blockIdx.x, tid=threadIdx.x;
    __shared__ float gls[MAXGRID];
    __shared__ float ze[64];
    __shared__ float pred[4];
    const int* wsi=(const int*)wsf; int nit=wsi[WS_NIT];
    for (int i=tid;i<MAXGRID;i+=128) gls[i]=wsf[WS_GRID+i];
    __syncthreads();
    int sl = seq[b];
    float tq = (float)tp[b*T + sl-1] / FSCALE;
    int lo=0,hi=nit;
    while(lo<hi){int mid=(lo+hi)>>1; if (gls[mid]<=tq) lo=mid+1; else hi=mid;}
    int k=lo-1; if(k<0)k=0; if(nit>=2 && k>nit-2)k=nit-2; if (nit<2) k=0;
    float w=0.f;
    if (nit>=2){ float tl=gls[k],tr=gls[k+1]; float den=(tr-tl==0.f)?1.f:(tr-tl); w=(tq-tl)/den; }
    if (tid<LAT){
        size_t o0 = (size_t)WS_YS + ((size_t)k*B+b)*LAT+tid;
        float zl = wsf[o0]*(1.f-w) + ((nit>=2)? wsf[o0+(size_t)B*LAT]*w : 0.f);
        ze[tid]=zl;
        out[1026 + b*LAT + tid] = zl;
    }
    __syncthreads();
    float hj = bs1[tid];
    #pragma unroll 8
    for (int l=0;l<LAT;++l) hj = fmaf(ze[l], Ws1[l*HID+tid], hj);
    hj = fmaf(age[b], Ws1[LAT*HID+tid], hj);
    hj = fmaxf(hj,0.f);
    float p0 = hj*Ws2[tid*2+0], p1 = hj*Ws2[tid*2+1];
    #pragma unroll
    for (int off=32;off>0;off>>=1){ p0 += __shfl_down(p0,off); p1 += __shfl_down(p1,off); }
    int wv = tid>>6;
    if ((tid&63)==0){ pred[wv*2]=p0; pred[wv*2+1]=p1; }
    __syncthreads();
    if (tid==0){
        out[b*2+0] = bs2[0] + pred[0]+pred[2];
        out[b*2+1] = bs2[1] + pred[1]+pred[3];
    }
}

// ---------------- kernel 7: finalize scalars ----------------
__global__ void k_fin(float* wsf, float* out){
    float n = wsf[WS_NO];
    out[1024] = (n>0.f) ? (wsf[WS_RE]/fmaxf(n,1.f)) : 0.f;
    out[1025] = -0.5f * (wsf[WS_KL] / (float)B);
}

extern "C" void kernel_launch(void* const* d_in, const int* in_sizes, int n_in,
                              void* d_out, int out_size, void* d_ws, size_t ws_size,
                              hipStream_t stream) {
    const float* obs   = (const float*)d_in[0];
    const float* age   = (const float*)d_in[1];
    const float* eps   = (const float*)d_in[2];
    const float* Wih   = (const float*)d_in[3];
    const float* Whh   = (const float*)d_in[4];
    const float* bih   = (const float*)d_in[5];
    const float* bhh   = (const float*)d_in[6];
    const float* Wmu   = (const float*)d_in[7];
    const float* bmu   = (const float*)d_in[8];
    const float* Wlv   = (const float*)d_in[9];
    const float* blv   = (const float*)d_in[10];
    const float* W1    = (const float*)d_in[11];
    const float* b1    = (const float*)d_in[12];
    const float* W2    = (const float*)d_in[13];
    const float* b2    = (const float*)d_in[14];
    const float* W3    = (const float*)d_in[15];
    const float* b3    = (const float*)d_in[16];
    const float* Wo1   = (const float*)d_in[17];
    const float* bo1   = (const float*)d_in[18];
    const float* Wo2   = (const float*)d_in[19];
    const float* bo2   = (const float*)d_in[20];
    const float* Ws1   = (const float*)d_in[21];
    const float* bs1   = (const float*)d_in[22];
    const float* Ws2   = (const float*)d_in[23];
    const float* bs2   = (const float*)d_in[24];
    const int*   maskI = (const int*)d_in[25];
    const int*   tp    = (const int*)d_in[26];
    const int*   seq   = (const int*)d_in[27];
    float* wsf = (float*)d_ws;
    float* out = (float*)d_out;

    k_init<<<1, 256, 0, stream>>>(tp, wsf);
    k_grid<<<1, 128, 0, stream>>>(wsf);
    k_gru<<<B, 384, 0, stream>>>(obs, eps, Wih, Whh, bih, bhh, Wmu, bmu, Wlv, blv,
                                 maskI, tp, wsf);
    k_ode<<<B, 256, 0, stream>>>(W1, b1, W2, b2, W3, b3, wsf);
    k_recon<<<B, 128, 0, stream>>>(obs, maskI, tp, seq, Wo1, bo1, Wo2, bo2, wsf);
    k_surv<<<B, 128, 0, stream>>>(age, tp, seq, Ws1, bs1, Ws2, bs2, wsf, out);
    k_fin<<<1, 1, 0, stream>>>(wsf, out);
}

// Round 2
// 931.384 us; speedup vs baseline: 1.0951x; 1.0951x over previous
//
#include <hip/hip_runtime.h>
#include <hip/hip_bf16.h>
#include <math.h>

#define B 512
#define T 64
#define NL 32
#define LAT 64
#define HID 128
#define DIN 65
#define G3 384
#define FSCALE 365.0f
#define MAXGRID 128
#define R_ODE 16

// ws layout (float index)
#define WS_MIN   0   // int
#define WS_MAX   1   // int
#define WS_NIT   2   // int
#define WS_KL    3
#define WS_RE    4
#define WS_NO    5
#define WS_GRID  8                 // MAXGRID floats
#define WS_Z0    (WS_GRID + MAXGRID)
#define WS_YS    (WS_Z0 + B*LAT)   // MAXGRID * B * LAT floats

typedef __attribute__((ext_vector_type(8))) __bf16 bf16x8;
typedef __attribute__((ext_vector_type(4))) float f32x4;

static __device__ __forceinline__ unsigned bf16_rne(float f){
    union { float f; unsigned u; } v; v.f = f;
    unsigned r = v.u + 0x7fffu + ((v.u >> 16) & 1u);
    return r >> 16;
}
static __device__ __forceinline__ float bf_lo(unsigned p){
    union { unsigned u; float f; } v; v.u = p << 16; return v.f;
}
static __device__ __forceinline__ float bf_hi(unsigned p){
    union { unsigned u; float f; } v; v.u = p & 0xffff0000u; return v.f;
}
// tanh(x) = 1 - 2/(exp(2x)+1); exp2-based, v_exp+v_rcp. Handles +-inf naturally.
static __device__ __forceinline__ float tanh_fast(float x){
    float t = __builtin_amdgcn_exp2f(x * 2.8853900817779268f);
    return 1.0f - 2.0f * __builtin_amdgcn_rcpf(t + 1.0f);
}
static __device__ __forceinline__ float sigmoid_fast(float x){
    return __builtin_amdgcn_rcpf(1.0f + __builtin_amdgcn_exp2f(-1.4426950408889634f * x));
}

// ---------------- kernel 1: init accumulators + min/max of timepoints ----------------
__global__ void k_init(const int* __restrict__ tp, float* wsf){
    int* wsi = (int*)wsf;
    __shared__ int smin[256], smax[256];
    int tid = threadIdx.x;
    int mn = 2147483647, mx = -2147483647-1;
    for (int i = tid; i < B*T; i += 256){ int v = tp[i]; mn = min(mn,v); mx = max(mx,v); }
    smin[tid]=mn; smax[tid]=mx; __syncthreads();
    for (int s=128; s>0; s>>=1){
        if (tid<s){ smin[tid]=min(smin[tid],smin[tid+s]); smax[tid]=max(smax[tid],smax[tid+s]); }
        __syncthreads();
    }
    if (tid==0){
        wsi[WS_MIN]=smin[0]; wsi[WS_MAX]=smax[0];
        wsf[WS_KL]=0.f; wsf[WS_RE]=0.f; wsf[WS_NO]=0.f;
    }
}

// ---------------- kernel 2: build integration grid (f64 to match numpy) ----------------
__global__ void k_grid(float* wsf){
    int* wsi=(int*)wsf;
    float t0f = (float)wsi[WS_MIN] / FSCALE;
    float t1f = (float)wsi[WS_MAX] / FSCALE;
    double t0d = (double)t0f, t1d = (double)t1f;
    int nit = (int)ceil((t1d-t0d)/0.05 + 1.0);
    if (nit < 1) nit = 1;
    if (nit > MAXGRID) nit = MAXGRID;
    if (threadIdx.x==0) wsi[WS_NIT] = nit;
    int k = threadIdx.x;
    if (k < nit){
        double g = (double)k * 0.05 + t0d;
        if (k == nit-1 && g > t1d) g = t1d;
        wsf[WS_GRID + k] = (float)g;
    }
}

// ---------------- kernel 3: GRU encoder (1 row/block, weights bf16 in VGPRs) ----------------
__global__ __launch_bounds__(384) void k_gru(
    const float* __restrict__ obs, const float* __restrict__ eps,
    const float* __restrict__ Wih, const float* __restrict__ Whh,
    const float* __restrict__ bih, const float* __restrict__ bhh,
    const float* __restrict__ Wmu, const float* __restrict__ bmu,
    const float* __restrict__ Wlv, const float* __restrict__ blv,
    const int* __restrict__ maskI, const int* __restrict__ tp,
    float* wsf)
{
    int b = blockIdx.x, j = threadIdx.x;
    __shared__ float xs[72];
    __shared__ float hs[HID];
    __shared__ float gbi[G3], gbh[G3];

    unsigned wih[33], whh[64];
    #pragma unroll
    for (int i=0;i<33;++i){
        float lo = Wih[(2*i)*G3 + j];
        float hi = (2*i+1 < DIN) ? Wih[(2*i+1)*G3 + j] : 0.f;
        wih[i] = (bf16_rne(lo)) | (bf16_rne(hi)<<16);
    }
    #pragma unroll
    for (int i=0;i<64;++i){
        float lo = Whh[(2*i)*G3 + j];
        float hi = Whh[(2*i+1)*G3 + j];
        whh[i] = (bf16_rne(lo)) | (bf16_rne(hi)<<16);
    }
    float bi = bih[j], bh = bhh[j];
    if (j < HID) hs[j] = 0.f;
    if (j >= 65 && j < 72) xs[j] = 0.f;
    __syncthreads();

    for (int s=0;s<T;++s){
        int t = T-1-s;
        if (j < NL){
            float mv = (float)maskI[(b*T + t)*NL + j];
            xs[j] = obs[(b*T + t)*NL + j] * mv;
            xs[NL + j] = mv;
        } else if (j == 64){
            float d = 0.f;
            if (t > 0) d = (float)(tp[b*T+t] - tp[b*T+t-1]);
            xs[64] = d;
        }
        __syncthreads();
        // gi: 2 accumulators, gh: 4 accumulators (break dependent FMA chains)
        float ga = bi, gb = 0.f;
        #pragma unroll
        for (int i=0;i<32;i+=2){
            unsigned p0 = wih[i], p1 = wih[i+1];
            ga = fmaf(xs[2*i],   bf_lo(p0), ga); ga = fmaf(xs[2*i+1], bf_hi(p0), ga);
            gb = fmaf(xs[2*i+2], bf_lo(p1), gb); gb = fmaf(xs[2*i+3], bf_hi(p1), gb);
        }
        { unsigned p = wih[32]; ga = fmaf(xs[64], bf_lo(p), ga); ga = fmaf(xs[65], bf_hi(p), ga); }
        float gi = ga + gb;
        float h0 = bh, h1a = 0.f, h2a = 0.f, h3a = 0.f;
        #pragma unroll
        for (int i=0;i<64;i+=4){
            unsigned p0 = whh[i], p1 = whh[i+1], p2 = whh[i+2], p3 = whh[i+3];
            h0  = fmaf(hs[2*i],   bf_lo(p0), h0 ); h0  = fmaf(hs[2*i+1], bf_hi(p0), h0 );
            h1a = fmaf(hs[2*i+2], bf_lo(p1), h1a); h1a = fmaf(hs[2*i+3], bf_hi(p1), h1a);
            h2a = fmaf(hs[2*i+4], bf_lo(p2), h2a); h2a = fmaf(hs[2*i+5], bf_hi(p2), h2a);
            h3a = fmaf(hs[2*i+6], bf_lo(p3), h3a); h3a = fmaf(hs[2*i+7], bf_hi(p3), h3a);
        }
        float gh = (h0 + h1a) + (h2a + h3a);
        gbi[j] = gi; gbh[j] = gh;
        __syncthreads();
        if (j < HID){
            float r  = sigmoid_fast(gbi[j] + gbh[j]);
            float zg = sigmoid_fast(gbi[j+HID] + gbh[j+HID]);
            float n  = tanh_fast(gbi[j+2*HID] + r*gbh[j+2*HID]);
            hs[j] = (1.f - zg)*n + zg*hs[j];
        }
        __syncthreads();
    }

    if (j < LAT){
        float mu = bmu[j], lv = blv[j];
        float mu2 = 0.f, lv2 = 0.f;
        #pragma unroll 8
        for (int k=0;k<HID;k+=2){
            mu  = fmaf(hs[k],   Wmu[k*LAT + j],       mu);
            mu2 = fmaf(hs[k+1], Wmu[(k+1)*LAT + j],   mu2);
            lv  = fmaf(hs[k],   Wlv[k*LAT + j],       lv);
            lv2 = fmaf(hs[k+1], Wlv[(k+1)*LAT + j],   lv2);
        }
        mu += mu2; lv += lv2;
        float z0 = mu + eps[b*LAT + j]*expf(0.5f*lv);
        wsf[WS_Z0 + b*LAT + j] = z0;
        wsf[WS_YS + (size_t)b*LAT + j] = z0;  // ys[0]
        float term = 1.f + lv - mu*mu - expf(lv);
        #pragma unroll
        for (int off=32; off>0; off>>=1) term += __shfl_down(term, off);
        if (j==0) atomicAdd(&wsf[WS_KL], term);
    }
}

// ---------------- kernel 4: RK4 ODE via MFMA, 16 rows/block ----------------
// A frag (16x16x32 bf16): lane holds A[lane&15][8*(lane>>4)+e]  (m92/m97 load pattern)
// B frag:                 lane holds B[8*(lane>>4)+e][lane&15]
// C/D:                    lane holds C[4*(lane>>4)+j][lane&15]  (m89 verified)
__global__ __launch_bounds__(256) void k_ode(
    const float* __restrict__ W1, const float* __restrict__ b1,
    const float* __restrict__ W2, const float* __restrict__ b2,
    const float* __restrict__ W3, const float* __restrict__ b3,
    float* wsf)
{
    const int b0 = blockIdx.x * R_ODE;
    const int tid = threadIdx.x;
    const int w = tid >> 6, lane = tid & 63;
    const int g = lane >> 4, c = lane & 15;
    const int* wsi = (const int*)wsf;
    const int nit = wsi[WS_NIT];

    __shared__ __align__(16) __bf16 zin[16][72];   // row stride 144B == 4 banks mod 32
    __shared__ __align__(16) __bf16 h1s[16][136];  // row stride 272B == 4 banks mod 32
    __shared__ __align__(16) __bf16 h2s[16][136];
    __shared__ float gls[MAXGRID];

    // ---- preload weight B-fragments (bf16 in VGPRs) ----
    // wave w owns output cols [32w,32w+32) for stages 1&2 (tiles t=0,1), cols [16w,16w+16) for stage 3
    bf16x8 w1f[2][2];   // [tile][k-half(32)]
    bf16x8 w2f[2][4];   // [tile][k-quarter(32)]
    bf16x8 w3f[4];      // [k-quarter(32)]
    #pragma unroll
    for (int t=0;t<2;++t)
        #pragma unroll
        for (int q=0;q<2;++q)
            #pragma unroll
            for (int e=0;e<8;++e)
                w1f[t][q][e] = (__bf16)W1[(q*32+g*8+e)*HID + w*32+t*16+c];
    #pragma unroll
    for (int t=0;t<2;++t)
        #pragma unroll
        for (int q=0;q<4;++q)
            #pragma unroll
            for (int e=0;e<8;++e)
                w2f[t][q][e] = (__bf16)W2[(q*32+g*8+e)*HID + w*32+t*16+c];
    #pragma unroll
    for (int q=0;q<4;++q)
        #pragma unroll
        for (int e=0;e<8;++e)
            w3f[q][e] = (__bf16)W3[(q*32+g*8+e)*LAT + w*16+c];
    const float b1v0 = b1[w*32+c],    b1v1 = b1[w*32+16+c];
    const float b2v0 = b2[w*32+c],    b2v1 = b2[w*32+16+c];
    const float b3v  = b3[w*16+c];

    // ---- init RK4 state: y in stage-3 C-layout registers ----
    float y[4], facc[4];
    #pragma unroll
    for (int j=0;j<4;++j){
        y[j] = wsf[WS_Z0 + (size_t)(b0 + 4*g + j)*LAT + w*16 + c];
        zin[4*g+j][w*16+c] = (__bf16)y[j];
        facc[j] = 0.f;
    }
    for (int kk=tid; kk<MAXGRID; kk+=256) gls[kk] = wsf[WS_GRID+kk];
    __syncthreads();

    for (int i=0; i<nit-1; ++i){
        float h = gls[i+1]-gls[i];
        #pragma unroll
        for (int sub=0; sub<4; ++sub){
            // ---- stage 1: H1 = tanh(Z @ W1 + b1), 16x64 @ 64x128 ----
            f32x4 a0c = {0.f,0.f,0.f,0.f}, a1c = {0.f,0.f,0.f,0.f};
            {
                bf16x8 az0 = *(const bf16x8*)&zin[c][g*8];
                bf16x8 az1 = *(const bf16x8*)&zin[c][32+g*8];
                a0c = __builtin_amdgcn_mfma_f32_16x16x32_bf16(az0, w1f[0][0], a0c, 0,0,0);
                a0c = __builtin_amdgcn_mfma_f32_16x16x32_bf16(az1, w1f[0][1], a0c, 0,0,0);
                a1c = __builtin_amdgcn_mfma_f32_16x16x32_bf16(az0, w1f[1][0], a1c, 0,0,0);
                a1c = __builtin_amdgcn_mfma_f32_16x16x32_bf16(az1, w1f[1][1], a1c, 0,0,0);
            }
            #pragma unroll
            for (int j=0;j<4;++j){
                h1s[4*g+j][w*32+c]    = (__bf16)tanh_fast(a0c[j] + b1v0);
                h1s[4*g+j][w*32+16+c] = (__bf16)tanh_fast(a1c[j] + b1v1);
            }
            __syncthreads();
            // ---- stage 2: H2 = tanh(H1 @ W2 + b2), 16x128 @ 128x128 ----
            f32x4 c20 = {0.f,0.f,0.f,0.f}, c21 = {0.f,0.f,0.f,0.f};
            #pragma unroll
            for (int q=0;q<4;++q){
                bf16x8 aq = *(const bf16x8*)&h1s[c][q*32+g*8];
                c20 = __builtin_amdgcn_mfma_f32_16x16x32_bf16(aq, w2f[0][q], c20, 0,0,0);
                c21 = __builtin_amdgcn_mfma_f32_16x16x32_bf16(aq, w2f[1][q], c21, 0,0,0);
            }
            #pragma unroll
            for (int j=0;j<4;++j){
                h2s[4*g+j][w*32+c]    = (__bf16)tanh_fast(c20[j] + b2v0);
                h2s[4*g+j][w*32+16+c] = (__bf16)tanh_fast(c21[j] + b2v1);
            }
            __syncthreads();
            // ---- stage 3: F = H2 @ W3 + b3, 16x128 @ 128x64 ----
            f32x4 c3 = {0.f,0.f,0.f,0.f};
            #pragma unroll
            for (int q=0;q<4;++q){
                bf16x8 aq = *(const bf16x8*)&h2s[c][q*32+g*8];
                c3 = __builtin_amdgcn_mfma_f32_16x16x32_bf16(aq, w3f[q], c3, 0,0,0);
            }
            // ---- RK4 epilogue (state lives in this lane's registers) ----
            #pragma unroll
            for (int j=0;j<4;++j){
                float f = c3[j] + b3v;
                float zn;
                if (sub==0){ facc[j] = f;         zn = fmaf(0.5f*h, f, y[j]); }
                else if (sub==1){ facc[j] += 2.f*f; zn = fmaf(0.5f*h, f, y[j]); }
                else if (sub==2){ facc[j] += 2.f*f; zn = fmaf(h, f, y[j]); }
                else {
                    facc[j] += f;
                    y[j] = fmaf(h*(1.0f/6.0f), facc[j], y[j]);
                    zn = y[j];
                    wsf[WS_YS + ((size_t)(i+1)*B + (b0+4*g+j))*LAT + w*16 + c] = y[j];
                }
                zin[4*g+j][w*16+c] = (__bf16)zn;
            }
            __syncthreads();
        }
    }
}

// ---------------- kernel 5: interpolation + decoder + masked MSE / n_obs ----------------
__global__ __launch_bounds__(128) void k_recon(
    const float* __restrict__ obs, const int* __restrict__ maskI,
    const int* __restrict__ tp, const int* __restrict__ seq,
    const float* __restrict__ Wo1, const float* __restrict__ bo1,
    const float* __restrict__ Wo2, const float* __restrict__ bo2,
    float* wsf)
{
    int b = blockIdx.x, tg = blockIdx.y, tid = threadIdx.x;
    __shared__ __align__(16) float wo1[LAT*HID];
    __shared__ __align__(16) float wo2[HID*NL];
    __shared__ float bo1s[HID];
    __shared__ float bo2s[NL];
    __shared__ float gls[MAXGRID];
    __shared__ float zbt[64], hb[HID], p2[4][NL], red[32];
    const int* wsi=(const int*)wsf;
    int nit = wsi[WS_NIT];
    for (int i=tid;i<LAT*HID/4;i+=128) ((float4*)wo1)[i] = ((const float4*)Wo1)[i];
    for (int i=tid;i<HID*NL/4;i+=128)  ((float4*)wo2)[i] = ((const float4*)Wo2)[i];
    if (tid<HID) bo1s[tid]=bo1[tid];
    if (tid<NL)  bo2s[tid]=bo2[tid];
    for (int i=tid;i<MAXGRID;i+=128) gls[i]=wsf[WS_GRID+i];
    int sl = seq[b];
    float esum=0.f, ncnt=0.f;
    __syncthreads();
    for (int t=tg*16; t<tg*16+16; ++t){
        float tq = (float)tp[b*T+t] / FSCALE;
        int lo=0, hi=nit;
        while (lo<hi){ int mid=(lo+hi)>>1; if (gls[mid]<=tq) lo=mid+1; else hi=mid; }
        int k = lo-1; if (k<0) k=0; if (nit>=2 && k>nit-2) k=nit-2; if (nit<2) k=0;
        float w=0.f;
        if (nit>=2){ float tl=gls[k], tr=gls[k+1]; float den=(tr-tl==0.f)?1.f:(tr-tl); w=(tq-tl)/den; }
        if (tid<LAT){
            size_t o0 = (size_t)WS_YS + ((size_t)k*B + b)*LAT + tid;
            float zl = wsf[o0]*(1.f-w) + ((nit>=2)? wsf[o0 + (size_t)B*LAT]*w : 0.f);
            zbt[tid]=zl;
        }
        __syncthreads();
        float hj = bo1s[tid], hj2 = 0.f;
        #pragma unroll 8
        for (int l=0;l<LAT;l+=2){
            hj  = fmaf(zbt[l],   wo1[l*HID+tid],     hj);
            hj2 = fmaf(zbt[l+1], wo1[(l+1)*HID+tid], hj2);
        }
        hj = fmaxf(hj + hj2, 0.f);
        hb[tid] = hj;
        __syncthreads();
        {
            int o = tid & 31, q = tid >> 5;
            float ps = 0.f, ps2 = 0.f;
            #pragma unroll 8
            for (int kk=0;kk<32;kk+=2){
                ps  = fmaf(hb[q*32+kk],   wo2[(q*32+kk)*NL + o],   ps);
                ps2 = fmaf(hb[q*32+kk+1], wo2[(q*32+kk+1)*NL + o], ps2);
            }
            p2[q][o] = ps + ps2;
        }
        __syncthreads();
        if (tid < NL){
            float xh = bo2s[tid] + p2[0][tid]+p2[1][tid]+p2[2][tid]+p2[3][tid];
            float mv = (float)maskI[(b*T+t)*NL+tid] * ((t<sl)?1.f:0.f);
            float d = xh - obs[(b*T+t)*NL+tid];
            esum = fmaf(mv*d, d, esum);
            ncnt += mv;
        }
        __syncthreads();
    }
    if (tid<NL) red[tid]=esum;
    __syncthreads();
    if (tid==0){ float s=0.f; for(int i=0;i<32;++i) s+=red[i]; atomicAdd(&wsf[WS_RE], s); }
    __syncthreads();
    if (tid<NL) red[tid]=ncnt;
    __syncthreads();
    if (tid==0){ float s=0.f; for(int i=0;i<32;++i) s+=red[i]; atomicAdd(&wsf[WS_NO], s); }
}

// ---------------- kernel 6: z_eval + survival head ----------------
__global__ __launch_bounds__(128) void k_surv(
    const float* __restrict__ age, const int* __restrict__ tp, const int* __restrict__ seq,
    const float* __restrict__ Ws1, const float* __restrict__ bs1,
    const float* __restrict__ Ws2, const float* __restrict__ bs2,
    float* wsf, float* out)
{
    int b=blockIdx.x, tid=threadIdx.x;
    __shared__ float gls[MAXGRID];
    __shared__ float ze[64];
    __shared__ float pred[4];
    const int* wsi=(const int*)wsf; int nit=wsi[WS_NIT];
    for (int i=tid;i<MAXGRID;i+=128) gls[i]=wsf[WS_GRID+i];
    __syncthreads();
    int sl = seq[b];
    float tq = (float)tp[b*T + sl-1] / FSCALE;
    int lo=0,hi=nit;
    while(lo<hi){int mid=(lo+hi)>>1; if (gls[mid]<=tq) lo=mid+1; else hi=mid;}
    int k=lo-1; if(k<0)k=0; if(nit>=2 && k>nit-2)k=nit-2; if (nit<2) k=0;
    float w=0.f;
    if (nit>=2){ float tl=gls[k],tr=gls[k+1]; float den=(tr-tl==0.f)?1.f:(tr-tl); w=(tq-tl)/den; }
    if (tid<LAT){
        size_t o0 = (size_t)WS_YS + ((size_t)k*B+b)*LAT+tid;
        float zl = wsf[o0]*(1.f-w) + ((nit>=2)? wsf[o0+(size_t)B*LAT]*w : 0.f);
        ze[tid]=zl;
        out[1026 + b*LAT + tid] = zl;
    }
    __syncthreads();
    float hj = bs1[tid];
    #pragma unroll 8
    for (int l=0;l<LAT;++l) hj = fmaf(ze[l], Ws1[l*HID+tid], hj);
    hj = fmaf(age[b], Ws1[LAT*HID+tid], hj);
    hj = fmaxf(hj,0.f);
    float p0 = hj*Ws2[tid*2+0], p1 = hj*Ws2[tid*2+1];
    #pragma unroll
    for (int off=32;off>0;off>>=1){ p0 += __shfl_down(p0,off); p1 += __shfl_down(p1,off); }
    int wv = tid>>6;
    if ((tid&63)==0){ pred[wv*2]=p0; pred[wv*2+1]=p1; }
    __syncthreads();
    if (tid==0){
        out[b*2+0] = bs2[0] + pred[0]+pred[2];
        out[b*2+1] = bs2[1] + pred[1]+pred[3];
    }
}

// ---------------- kernel 7: finalize scalars ----------------
__global__ void k_fin(float* wsf, float* out){
    float n = wsf[WS_NO];
    out[1024] = (n>0.f) ? (wsf[WS_RE]/fmaxf(n,1.f)) : 0.f;
    out[1025] = -0.5f * (wsf[WS_KL] / (float)B);
}

extern "C" void kernel_launch(void* const* d_in, const int* in_sizes, int n_in,
                              void* d_out, int out_size, void* d_ws, size_t ws_size,
                              hipStream_t stream) {
    const float* obs   = (const float*)d_in[0];
    const float* age   = (const float*)d_in[1];
    const float* eps   = (const float*)d_in[2];
    const float* Wih   = (const float*)d_in[3];
    const float* Whh   = (const float*)d_in[4];
    const float* bih   = (const float*)d_in[5];
    const float* bhh   = (const float*)d_in[6];
    const float* Wmu   = (const float*)d_in[7];
    const float* bmu   = (const float*)d_in[8];
    const float* Wlv   = (const float*)d_in[9];
    const float* blv   = (const float*)d_in[10];
    const float* W1    = (const float*)d_in[11];
    const float* b1    = (const float*)d_in[12];
    const float* W2    = (const float*)d_in[13];
    const float* b2    = (const float*)d_in[14];
    const float* W3    = (const float*)d_in[15];
    const float* b3    = (const float*)d_in[16];
    const float* Wo1   = (const float*)d_in[17];
    const float* bo1   = (const float*)d_in[18];
    const float* Wo2   = (const float*)d_in[19];
    const float* bo2   = (const float*)d_in[20];
    const float* Ws1   = (const float*)d_in[21];
    const float* bs1   = (const float*)d_in[22];
    const float* Ws2   = (const float*)d_in[23];
    const float* bs2   = (const float*)d_in[24];
    const int*   maskI = (const int*)d_in[25];
    const int*   tp    = (const int*)d_in[26];
    const int*   seq   = (const int*)d_in[27];
    float* wsf = (float*)d_ws;
    float* out = (float*)d_out;

    k_init<<<1, 256, 0, stream>>>(tp, wsf);
    k_grid<<<1, 128, 0, stream>>>(wsf);
    k_gru<<<B, 384, 0, stream>>>(obs, eps, Wih, Whh, bih, bhh, Wmu, bmu, Wlv, blv,
                                 maskI, tp, wsf);
    k_ode<<<B/R_ODE, 256, 0, stream>>>(W1, b1, W2, b2, W3, b3, wsf);
    k_recon<<<dim3(B,4), 128, 0, stream>>>(obs, maskI, tp, seq, Wo1, bo1, Wo2, bo2, wsf);
    k_surv<<<B, 128, 0, stream>>>(age, tp, seq, Ws1, bs1, Ws2, bs2, wsf, out);
    k_fin<<<1, 1, 0, stream>>>(wsf, out);
}

// Round 3
// 798.391 us; speedup vs baseline: 1.2776x; 1.1666x over previous
//
#include <hip/hip_runtime.h>
#include <hip/hip_bf16.h>
#include <math.h>

#define B 512
#define T 64
#define NL 32
#define LAT 64
#define HID 128
#define DIN 65
#define G3 384
#define FSCALE 365.0f
#define MAXGRID 128
#define R_ODE 16

// ws layout (float index)
#define WS_MIN   0   // int
#define WS_MAX   1   // int
#define WS_NIT   2   // int
#define WS_KL    3
#define WS_RE    4
#define WS_NO    5
#define WS_GRID  8                 // MAXGRID floats
#define WS_Z0    (WS_GRID + MAXGRID)
#define WS_YS    (WS_Z0 + B*LAT)   // MAXGRID * B * LAT floats

typedef __attribute__((ext_vector_type(8))) __bf16 bf16x8;
typedef __attribute__((ext_vector_type(4))) float f32x4;

static __device__ __forceinline__ unsigned bf16_rne(float f){
    union { float f; unsigned u; } v; v.f = f;
    unsigned r = v.u + 0x7fffu + ((v.u >> 16) & 1u);
    return r >> 16;
}
static __device__ __forceinline__ float bf_lo(unsigned p){
    union { unsigned u; float f; } v; v.u = p << 16; return v.f;
}
static __device__ __forceinline__ float bf_hi(unsigned p){
    union { unsigned u; float f; } v; v.u = p & 0xffff0000u; return v.f;
}
// tanh(x) = 1 - 2/(exp(2x)+1); exp2-based, v_exp+v_rcp. Handles +-inf naturally.
static __device__ __forceinline__ float tanh_fast(float x){
    float t = __builtin_amdgcn_exp2f(x * 2.8853900817779268f);
    return 1.0f - 2.0f * __builtin_amdgcn_rcpf(t + 1.0f);
}
static __device__ __forceinline__ float sigmoid_fast(float x){
    return __builtin_amdgcn_rcpf(1.0f + __builtin_amdgcn_exp2f(-1.4426950408889634f * x));
}

// ---------------- kernel 1: init accumulators + min/max of timepoints ----------------
__global__ void k_init(const int* __restrict__ tp, float* wsf){
    int* wsi = (int*)wsf;
    __shared__ int smin[256], smax[256];
    int tid = threadIdx.x;
    int mn = 2147483647, mx = -2147483647-1;
    for (int i = tid; i < B*T; i += 256){ int v = tp[i]; mn = min(mn,v); mx = max(mx,v); }
    smin[tid]=mn; smax[tid]=mx; __syncthreads();
    for (int s=128; s>0; s>>=1){
        if (tid<s){ smin[tid]=min(smin[tid],smin[tid+s]); smax[tid]=max(smax[tid],smax[tid+s]); }
        __syncthreads();
    }
    if (tid==0){
        wsi[WS_MIN]=smin[0]; wsi[WS_MAX]=smax[0];
        wsf[WS_KL]=0.f; wsf[WS_RE]=0.f; wsf[WS_NO]=0.f;
    }
}

// ---------------- kernel 2: build integration grid (f64 to match numpy) ----------------
__global__ void k_grid(float* wsf){
    int* wsi=(int*)wsf;
    float t0f = (float)wsi[WS_MIN] / FSCALE;
    float t1f = (float)wsi[WS_MAX] / FSCALE;
    double t0d = (double)t0f, t1d = (double)t1f;
    int nit = (int)ceil((t1d-t0d)/0.05 + 1.0);
    if (nit < 1) nit = 1;
    if (nit > MAXGRID) nit = MAXGRID;
    if (threadIdx.x==0) wsi[WS_NIT] = nit;
    int k = threadIdx.x;
    if (k < nit){
        double g = (double)k * 0.05 + t0d;
        if (k == nit-1 && g > t1d) g = t1d;
        wsf[WS_GRID + k] = (float)g;
    }
}

// ---------------- kernel 3: GRU encoder (1 row/block, weights bf16 in VGPRs) ----------------
__global__ __launch_bounds__(384) void k_gru(
    const float* __restrict__ obs, const float* __restrict__ eps,
    const float* __restrict__ Wih, const float* __restrict__ Whh,
    const float* __restrict__ bih, const float* __restrict__ bhh,
    const float* __restrict__ Wmu, const float* __restrict__ bmu,
    const float* __restrict__ Wlv, const float* __restrict__ blv,
    const int* __restrict__ maskI, const int* __restrict__ tp,
    float* wsf)
{
    int b = blockIdx.x, j = threadIdx.x;
    __shared__ __align__(16) float xs[72];
    __shared__ __align__(16) float hs[HID];
    __shared__ float gbi[G3], gbh[G3];

    unsigned wih[33], whh[64];
    #pragma unroll
    for (int i=0;i<33;++i){
        float lo = Wih[(2*i)*G3 + j];
        float hi = (2*i+1 < DIN) ? Wih[(2*i+1)*G3 + j] : 0.f;
        wih[i] = (bf16_rne(lo)) | (bf16_rne(hi)<<16);
    }
    #pragma unroll
    for (int i=0;i<64;++i){
        float lo = Whh[(2*i)*G3 + j];
        float hi = Whh[(2*i+1)*G3 + j];
        whh[i] = (bf16_rne(lo)) | (bf16_rne(hi)<<16);
    }
    float bi = bih[j], bh = bhh[j];
    if (j < HID) hs[j] = 0.f;
    if (j >= 65 && j < 72) xs[j] = 0.f;
    // initial xs for t = 63
    {
        int t0 = T-1;
        if (j < NL){
            float mv = (float)maskI[(b*T + t0)*NL + j];
            xs[j] = obs[(b*T + t0)*NL + j] * mv;
            xs[NL + j] = mv;
        } else if (j == 64){
            xs[64] = (float)(tp[b*T+t0] - tp[b*T+t0-1]);
        }
    }

    for (int s=0;s<T;++s){
        int t = T-1-s;
        __syncthreads();   // xs[t], hs ready
        // gi: 2 accumulators; gh: 4 accumulators; float4 LDS reads
        float ga = bi, gb = 0.f;
        const float4* X4 = (const float4*)xs;
        #pragma unroll
        for (int i=0;i<16;++i){
            float4 xv = X4[i];
            unsigned p0 = wih[2*i], p1 = wih[2*i+1];
            ga = fmaf(xv.x, bf_lo(p0), ga); ga = fmaf(xv.y, bf_hi(p0), ga);
            gb = fmaf(xv.z, bf_lo(p1), gb); gb = fmaf(xv.w, bf_hi(p1), gb);
        }
        ga = fmaf(xs[64], bf_lo(wih[32]), ga);
        float gi = ga + gb;
        float h0 = bh, h1a = 0.f, h2a = 0.f, h3a = 0.f;
        const float4* H4 = (const float4*)hs;
        #pragma unroll
        for (int i=0;i<16;++i){
            float4 ha = H4[2*i], hb4 = H4[2*i+1];
            unsigned p0 = whh[4*i], p1 = whh[4*i+1], p2 = whh[4*i+2], p3 = whh[4*i+3];
            h0  = fmaf(ha.x,  bf_lo(p0), h0 ); h0  = fmaf(ha.y,  bf_hi(p0), h0 );
            h1a = fmaf(ha.z,  bf_lo(p1), h1a); h1a = fmaf(ha.w,  bf_hi(p1), h1a);
            h2a = fmaf(hb4.x, bf_lo(p2), h2a); h2a = fmaf(hb4.y, bf_hi(p2), h2a);
            h3a = fmaf(hb4.z, bf_lo(p3), h3a); h3a = fmaf(hb4.w, bf_hi(p3), h3a);
        }
        float gh = (h0 + h1a) + (h2a + h3a);
        gbi[j] = gi; gbh[j] = gh;
        __syncthreads();
        if (j < HID){
            float r  = sigmoid_fast(gbi[j] + gbh[j]);
            float zg = sigmoid_fast(gbi[j+HID] + gbh[j+HID]);
            float n  = tanh_fast(gbi[j+2*HID] + r*gbh[j+2*HID]);
            hs[j] = (1.f - zg)*n + zg*hs[j];
        } else if (s < T-1){
            // idle threads prepare xs for the next step (t-1)
            int tn = t-1;
            if (j >= 256 && j < 256+NL){
                int j2 = j-256;
                float mv = (float)maskI[(b*T + tn)*NL + j2];
                xs[j2] = obs[(b*T + tn)*NL + j2] * mv;
                xs[NL + j2] = mv;
            } else if (j == 320){
                xs[64] = (tn > 0) ? (float)(tp[b*T+tn] - tp[b*T+tn-1]) : 0.f;
            }
        }
    }
    __syncthreads();

    if (j < LAT){
        float mu = bmu[j], lv = blv[j];
        float mu2 = 0.f, lv2 = 0.f;
        #pragma unroll 8
        for (int k=0;k<HID;k+=2){
            mu  = fmaf(hs[k],   Wmu[k*LAT + j],       mu);
            mu2 = fmaf(hs[k+1], Wmu[(k+1)*LAT + j],   mu2);
            lv  = fmaf(hs[k],   Wlv[k*LAT + j],       lv);
            lv2 = fmaf(hs[k+1], Wlv[(k+1)*LAT + j],   lv2);
        }
        mu += mu2; lv += lv2;
        float z0 = mu + eps[b*LAT + j]*expf(0.5f*lv);
        wsf[WS_Z0 + b*LAT + j] = z0;
        wsf[WS_YS + (size_t)b*LAT + j] = z0;  // ys[0]
        float term = 1.f + lv - mu*mu - expf(lv);
        #pragma unroll
        for (int off=32; off>0; off>>=1) term += __shfl_down(term, off);
        if (j==0) atomicAdd(&wsf[WS_KL], term);
    }
}

// ---------------- kernel 4: RK4 ODE via MFMA, 16 rows/block, 8 waves ----------------
// A frag (16x16x32 bf16): lane holds A[lane&15][8*(lane>>4)+e]
// B frag:                 lane holds B[8*(lane>>4)+e][lane&15]
// C/D:                    lane holds C[4*(lane>>4)+j][lane&15]
__global__ __launch_bounds__(512) void k_ode(
    const float* __restrict__ W1, const float* __restrict__ b1,
    const float* __restrict__ W2, const float* __restrict__ b2,
    const float* __restrict__ W3, const float* __restrict__ b3,
    float* wsf)
{
    const int b0 = blockIdx.x * R_ODE;
    const int tid = threadIdx.x;
    const int w = tid >> 6, lane = tid & 63;
    const int g = lane >> 4, c = lane & 15;
    const int w3c = 16*(w&3) + c;     // stage-3 column for waves 0-3
    const int* wsi = (const int*)wsf;
    const int nit = wsi[WS_NIT];

    __shared__ __align__(16) __bf16 zin[16][72];   // row stride 144B
    __shared__ __align__(16) __bf16 h1s[16][136];  // row stride 272B
    __shared__ __align__(16) __bf16 h2s[16][136];
    __shared__ float gls[MAXGRID];

    // ---- preload weight B-fragments: wave w owns cols [16w,16w+16) (stages 1,2);
    //      waves 0-3 own cols [16w,16w+16) of stage 3 ----
    bf16x8 w1f[2], w2f[4], w3f[4];
    #pragma unroll
    for (int q=0;q<2;++q)
        #pragma unroll
        for (int e=0;e<8;++e)
            w1f[q][e] = (__bf16)W1[(q*32+g*8+e)*HID + 16*w+c];
    #pragma unroll
    for (int q=0;q<4;++q)
        #pragma unroll
        for (int e=0;e<8;++e)
            w2f[q][e] = (__bf16)W2[(q*32+g*8+e)*HID + 16*w+c];
    #pragma unroll
    for (int q=0;q<4;++q)
        #pragma unroll
        for (int e=0;e<8;++e)
            w3f[q][e] = (__bf16)W3[(q*32+g*8+e)*LAT + w3c];
    const float b1v = b1[16*w+c];
    const float b2v = b2[16*w+c];
    const float b3v = b3[w3c];

    // ---- init RK4 state (waves 0-3): y in stage-3 C-layout registers ----
    float y[4], facc[4];
    if (w < 4){
        #pragma unroll
        for (int j=0;j<4;++j){
            y[j] = wsf[WS_Z0 + (size_t)(b0 + 4*g + j)*LAT + w3c];
            zin[4*g+j][w3c] = (__bf16)y[j];
            facc[j] = 0.f;
        }
    }
    for (int kk=tid; kk<MAXGRID; kk+=512) gls[kk] = wsf[WS_GRID+kk];
    __syncthreads();

    for (int i=0; i<nit-1; ++i){
        float h = gls[i+1]-gls[i];
        #pragma unroll
        for (int sub=0; sub<4; ++sub){
            // ---- stage 1: H1 = tanh(Z @ W1 + b1); wave w -> cols [16w,16w+16) ----
            f32x4 a1 = {0.f,0.f,0.f,0.f};
            {
                bf16x8 az0 = *(const bf16x8*)&zin[c][g*8];
                bf16x8 az1 = *(const bf16x8*)&zin[c][32+g*8];
                a1 = __builtin_amdgcn_mfma_f32_16x16x32_bf16(az0, w1f[0], a1, 0,0,0);
                a1 = __builtin_amdgcn_mfma_f32_16x16x32_bf16(az1, w1f[1], a1, 0,0,0);
            }
            #pragma unroll
            for (int j=0;j<4;++j)
                h1s[4*g+j][16*w+c] = (__bf16)tanh_fast(a1[j] + b1v);
            __syncthreads();
            // ---- stage 2: H2 = tanh(H1 @ W2 + b2); two split accumulators ----
            f32x4 c2a = {0.f,0.f,0.f,0.f}, c2b = {0.f,0.f,0.f,0.f};
            {
                bf16x8 aq0 = *(const bf16x8*)&h1s[c][g*8];
                bf16x8 aq1 = *(const bf16x8*)&h1s[c][32+g*8];
                bf16x8 aq2 = *(const bf16x8*)&h1s[c][64+g*8];
                bf16x8 aq3 = *(const bf16x8*)&h1s[c][96+g*8];
                c2a = __builtin_amdgcn_mfma_f32_16x16x32_bf16(aq0, w2f[0], c2a, 0,0,0);
                c2b = __builtin_amdgcn_mfma_f32_16x16x32_bf16(aq2, w2f[2], c2b, 0,0,0);
                c2a = __builtin_amdgcn_mfma_f32_16x16x32_bf16(aq1, w2f[1], c2a, 0,0,0);
                c2b = __builtin_amdgcn_mfma_f32_16x16x32_bf16(aq3, w2f[3], c2b, 0,0,0);
            }
            #pragma unroll
            for (int j=0;j<4;++j)
                h2s[4*g+j][16*w+c] = (__bf16)tanh_fast((c2a[j]+c2b[j]) + b2v);
            __syncthreads();
            // ---- stage 3 (waves 0-3): F = H2 @ W3 + b3 + RK4 epilogue ----
            if (w < 4){
                f32x4 c3a = {0.f,0.f,0.f,0.f}, c3b = {0.f,0.f,0.f,0.f};
                bf16x8 aq0 = *(const bf16x8*)&h2s[c][g*8];
                bf16x8 aq1 = *(const bf16x8*)&h2s[c][32+g*8];
                bf16x8 aq2 = *(const bf16x8*)&h2s[c][64+g*8];
                bf16x8 aq3 = *(const bf16x8*)&h2s[c][96+g*8];
                c3a = __builtin_amdgcn_mfma_f32_16x16x32_bf16(aq0, w3f[0], c3a, 0,0,0);
                c3b = __builtin_amdgcn_mfma_f32_16x16x32_bf16(aq2, w3f[2], c3b, 0,0,0);
                c3a = __builtin_amdgcn_mfma_f32_16x16x32_bf16(aq1, w3f[1], c3a, 0,0,0);
                c3b = __builtin_amdgcn_mfma_f32_16x16x32_bf16(aq3, w3f[3], c3b, 0,0,0);
                #pragma unroll
                for (int j=0;j<4;++j){
                    float f = (c3a[j]+c3b[j]) + b3v;
                    float zn;
                    if (sub==0){ facc[j] = f;         zn = fmaf(0.5f*h, f, y[j]); }
                    else if (sub==1){ facc[j] += 2.f*f; zn = fmaf(0.5f*h, f, y[j]); }
                    else if (sub==2){ facc[j] += 2.f*f; zn = fmaf(h, f, y[j]); }
                    else {
                        facc[j] += f;
                        y[j] = fmaf(h*(1.0f/6.0f), facc[j], y[j]);
                        zn = y[j];
                        wsf[WS_YS + ((size_t)(i+1)*B + (b0+4*g+j))*LAT + w3c] = y[j];
                    }
                    zin[4*g+j][w3c] = (__bf16)zn;
                }
            }
            __syncthreads();
        }
    }
}

// ---------------- kernel 5: recon via MFMA (1 block per b, 8 waves) ----------------
__global__ __launch_bounds__(512) void k_recon(
    const float* __restrict__ obs, const int* __restrict__ maskI,
    const int* __restrict__ tp, const int* __restrict__ seq,
    const float* __restrict__ Wo1, const float* __restrict__ bo1,
    const float* __restrict__ Wo2, const float* __restrict__ bo2,
    float* wsf)
{
    const int b = blockIdx.x, tid = threadIdx.x;
    const int w = tid >> 6, lane = tid & 63;
    const int g = lane >> 4, c = lane & 15;
    __shared__ __align__(16) __bf16 zbt[64][72];    // 64 t-rows x 64 lat
    __shared__ __align__(16) __bf16 hb[64][136];    // 64 t-rows x 128 hid
    __shared__ float gls[MAXGRID];
    __shared__ float red[16];
    const int* wsi=(const int*)wsf;
    const int nit = wsi[WS_NIT];
    for (int i=tid;i<MAXGRID;i+=512) gls[i]=wsf[WS_GRID+i];

    // weight fragments
    bf16x8 wo1f[2], wo2f[4];
    #pragma unroll
    for (int q=0;q<2;++q)
        #pragma unroll
        for (int e=0;e<8;++e)
            wo1f[q][e] = (__bf16)Wo1[(q*32+g*8+e)*HID + 16*w+c];
    {
        int n = w & 1;
        #pragma unroll
        for (int q=0;q<4;++q)
            #pragma unroll
            for (int e=0;e<8;++e)
                wo2f[q][e] = (__bf16)Wo2[(q*32+g*8+e)*NL + 16*n+c];
    }
    const float bo1v = bo1[16*w+c];
    const float bo2v = bo2[16*(w&1)+c];
    const int sl = seq[b];
    __syncthreads();

    // ---- interpolate zbt: thread handles (t = tid>>3, lats 8*(tid&7)..+7) ----
    {
        int t = tid >> 3, seg = tid & 7;
        float tq = (float)tp[b*T+t] / FSCALE;
        int lo=0, hi=nit;
        while (lo<hi){ int mid=(lo+hi)>>1; if (gls[mid]<=tq) lo=mid+1; else hi=mid; }
        int k = lo-1; if (k<0) k=0; if (nit>=2 && k>nit-2) k=nit-2; if (nit<2) k=0;
        float wq=0.f;
        if (nit>=2){ float tl=gls[k], tr=gls[k+1]; float den=(tr-tl==0.f)?1.f:(tr-tl); wq=(tq-tl)/den; }
        size_t o0 = (size_t)WS_YS + ((size_t)k*B + b)*LAT + seg*8;
        float4 za0 = *(const float4*)&wsf[o0];
        float4 za1 = *(const float4*)&wsf[o0+4];
        float4 zb0, zb1;
        if (nit>=2){
            zb0 = *(const float4*)&wsf[o0 + (size_t)B*LAT];
            zb1 = *(const float4*)&wsf[o0 + (size_t)B*LAT + 4];
        } else { zb0 = za0; zb1 = za1; }
        __bf16* dst = &zbt[t][seg*8];
        dst[0] = (__bf16)(za0.x*(1.f-wq)+zb0.x*wq);
        dst[1] = (__bf16)(za0.y*(1.f-wq)+zb0.y*wq);
        dst[2] = (__bf16)(za0.z*(1.f-wq)+zb0.z*wq);
        dst[3] = (__bf16)(za0.w*(1.f-wq)+zb0.w*wq);
        dst[4] = (__bf16)(za1.x*(1.f-wq)+zb1.x*wq);
        dst[5] = (__bf16)(za1.y*(1.f-wq)+zb1.y*wq);
        dst[6] = (__bf16)(za1.z*(1.f-wq)+zb1.z*wq);
        dst[7] = (__bf16)(za1.w*(1.f-wq)+zb1.w*wq);
    }
    __syncthreads();

    // ---- stage A: H = relu(zbt @ Wo1 + bo1); wave w -> cols [16w,16w+16), 4 M-tiles ----
    #pragma unroll
    for (int m=0;m<4;++m){
        f32x4 acc = {0.f,0.f,0.f,0.f};
        bf16x8 a0 = *(const bf16x8*)&zbt[16*m+c][g*8];
        bf16x8 a1 = *(const bf16x8*)&zbt[16*m+c][32+g*8];
        acc = __builtin_amdgcn_mfma_f32_16x16x32_bf16(a0, wo1f[0], acc, 0,0,0);
        acc = __builtin_amdgcn_mfma_f32_16x16x32_bf16(a1, wo1f[1], acc, 0,0,0);
        #pragma unroll
        for (int j=0;j<4;++j)
            hb[16*m+4*g+j][16*w+c] = (__bf16)fmaxf(acc[j] + bo1v, 0.f);
    }
    __syncthreads();

    // ---- stage B: xh = H @ Wo2 + bo2; wave w -> M-tile (w>>1), N-tile (w&1) ----
    float esum = 0.f, ncnt = 0.f;
    {
        int m = w >> 1, n = w & 1;
        f32x4 ca = {0.f,0.f,0.f,0.f}, cb = {0.f,0.f,0.f,0.f};
        bf16x8 a0 = *(const bf16x8*)&hb[16*m+c][g*8];
        bf16x8 a1 = *(const bf16x8*)&hb[16*m+c][32+g*8];
        bf16x8 a2 = *(const bf16x8*)&hb[16*m+c][64+g*8];
        bf16x8 a3 = *(const bf16x8*)&hb[16*m+c][96+g*8];
        ca = __builtin_amdgcn_mfma_f32_16x16x32_bf16(a0, wo2f[0], ca, 0,0,0);
        cb = __builtin_amdgcn_mfma_f32_16x16x32_bf16(a2, wo2f[2], cb, 0,0,0);
        ca = __builtin_amdgcn_mfma_f32_16x16x32_bf16(a1, wo2f[1], ca, 0,0,0);
        cb = __builtin_amdgcn_mfma_f32_16x16x32_bf16(a3, wo2f[3], cb, 0,0,0);
        #pragma unroll
        for (int j=0;j<4;++j){
            int t = 16*m + 4*g + j;
            int col = 16*n + c;
            float xh = (ca[j]+cb[j]) + bo2v;
            float mv = (float)maskI[(b*T+t)*NL+col] * ((t<sl)?1.f:0.f);
            float d = xh - obs[(b*T+t)*NL+col];
            esum = fmaf(mv*d, d, esum);
            ncnt += mv;
        }
    }
    // wave reduce, then block reduce
    #pragma unroll
    for (int off=32; off>0; off>>=1){
        esum += __shfl_xor(esum, off);
        ncnt += __shfl_xor(ncnt, off);
    }
    if (lane==0){ red[w] = esum; red[8+w] = ncnt; }
    __syncthreads();
    if (tid==0){
        float s=0.f, nn=0.f;
        #pragma unroll
        for (int i=0;i<8;++i){ s += red[i]; nn += red[8+i]; }
        atomicAdd(&wsf[WS_RE], s);
        atomicAdd(&wsf[WS_NO], nn);
    }
}

// ---------------- kernel 6: z_eval + survival head ----------------
__global__ __launch_bounds__(128) void k_surv(
    const float* __restrict__ age, const int* __restrict__ tp, const int* __restrict__ seq,
    const float* __restrict__ Ws1, const float* __restrict__ bs1,
    const float* __restrict__ Ws2, const float* __restrict__ bs2,
    float* wsf, float* out)
{
    int b=blockIdx.x, tid=threadIdx.x;
    __shared__ float gls[MAXGRID];
    __shared__ float ze[64];
    __shared__ float pred[4];
    const int* wsi=(const int*)wsf; int nit=wsi[WS_NIT];
    for (int i=tid;i<MAXGRID;i+=128) gls[i]=wsf[WS_GRID+i];
    __syncthreads();
    int sl = seq[b];
    float tq = (float)tp[b*T + sl-1] / FSCALE;
    int lo=0,hi=nit;
    while(lo<hi){int mid=(lo+hi)>>1; if (gls[mid]<=tq) lo=mid+1; else hi=mid;}
    int k=lo-1; if(k<0)k=0; if(nit>=2 && k>nit-2)k=nit-2; if (nit<2) k=0;
    float w=0.f;
    if (nit>=2){ float tl=gls[k],tr=gls[k+1]; float den=(tr-tl==0.f)?1.f:(tr-tl); w=(tq-tl)/den; }
    if (tid<LAT){
        size_t o0 = (size_t)WS_YS + ((size_t)k*B+b)*LAT+tid;
        float zl = wsf[o0]*(1.f-w) + ((nit>=2)? wsf[o0+(size_t)B*LAT]*w : 0.f);
        ze[tid]=zl;
        out[1026 + b*LAT + tid] = zl;
    }
    __syncthreads();
    float hj = bs1[tid];
    #pragma unroll 8
    for (int l=0;l<LAT;++l) hj = fmaf(ze[l], Ws1[l*HID+tid], hj);
    hj = fmaf(age[b], Ws1[LAT*HID+tid], hj);
    hj = fmaxf(hj,0.f);
    float p0 = hj*Ws2[tid*2+0], p1 = hj*Ws2[tid*2+1];
    #pragma unroll
    for (int off=32;off>0;off>>=1){ p0 += __shfl_down(p0,off); p1 += __shfl_down(p1,off); }
    int wv = tid>>6;
    if ((tid&63)==0){ pred[wv*2]=p0; pred[wv*2+1]=p1; }
    __syncthreads();
    if (tid==0){
        out[b*2+0] = bs2[0] + pred[0]+pred[2];
        out[b*2+1] = bs2[1] + pred[1]+pred[3];
    }
}

// ---------------- kernel 7: finalize scalars ----------------
__global__ void k_fin(float* wsf, float* out){
    float n = wsf[WS_NO];
    out[1024] = (n>0.f) ? (wsf[WS_RE]/fmaxf(n,1.f)) : 0.f;
    out[1025] = -0.5f * (wsf[WS_KL] / (float)B);
}

extern "C" void kernel_launch(void* const* d_in, const int* in_sizes, int n_in,
                              void* d_out, int out_size, void* d_ws, size_t ws_size,
                              hipStream_t stream) {
    const float* obs   = (const float*)d_in[0];
    const float* age   = (const float*)d_in[1];
    const float* eps   = (const float*)d_in[2];
    const float* Wih   = (const float*)d_in[3];
    const float* Whh   = (const float*)d_in[4];
    const float* bih   = (const float*)d_in[5];
    const float* bhh   = (const float*)d_in[6];
    const float* Wmu   = (const float*)d_in[7];
    const float* bmu   = (const float*)d_in[8];
    const float* Wlv   = (const float*)d_in[9];
    const float* blv   = (const float*)d_in[10];
    const float* W1    = (const float*)d_in[11];
    const float* b1    = (const float*)d_in[12];
    const float* W2    = (const float*)d_in[13];
    const float* b2    = (const float*)d_in[14];
    const float* W3    = (const float*)d_in[15];
    const float* b3    = (const float*)d_in[16];
    const float* Wo1   = (const float*)d_in[17];
    const float* bo1   = (const float*)d_in[18];
    const float* Wo2   = (const float*)d_in[19];
    const float* bo2   = (const float*)d_in[20];
    const float* Ws1   = (const float*)d_in[21];
    const float* bs1   = (const float*)d_in[22];
    const float* Ws2   = (const float*)d_in[23];
    const float* bs2   = (const float*)d_in[24];
    const int*   maskI = (const int*)d_in[25];
    const int*   tp    = (const int*)d_in[26];
    const int*   seq   = (const int*)d_in[27];
    float* wsf = (float*)d_ws;
    float* out = (float*)d_out;

    k_init<<<1, 256, 0, stream>>>(tp, wsf);
    k_grid<<<1, 128, 0, stream>>>(wsf);
    k_gru<<<B, 384, 0, stream>>>(obs, eps, Wih, Whh, bih, bhh, Wmu, bmu, Wlv, blv,
                                 maskI, tp, wsf);
    k_ode<<<B/R_ODE, 512, 0, stream>>>(W1, b1, W2, b2, W3, b3, wsf);
    k_recon<<<B, 512, 0, stream>>>(obs, maskI, tp, seq, Wo1, bo1, Wo2, bo2, wsf);
    k_surv<<<B, 128, 0, stream>>>(age, tp, seq, Ws1, bs1, Ws2, bs2, wsf, out);
    k_fin<<<1, 1, 0, stream>>>(wsf, out);
}

// Round 4
// 541.791 us; speedup vs baseline: 1.8826x; 1.4736x over previous
//
#include <hip/hip_runtime.h>
#include <hip/hip_bf16.h>
#include <math.h>

#define B 512
#define T 64
#define NL 32
#define LAT 64
#define HID 128
#define DIN 65
#define G3 384
#define FSCALE 365.0f
#define MAXGRID 128
#define R_ODE 16

// ws layout (float index)
#define WS_MIN   0   // int
#define WS_MAX   1   // int
#define WS_NIT   2   // int
#define WS_KL    3
#define WS_RE    4
#define WS_NO    5
#define WS_GRID  8                 // MAXGRID floats
#define WS_Z0    (WS_GRID + MAXGRID)
#define WS_YS    (WS_Z0 + B*LAT)   // MAXGRID * B * LAT floats

typedef __attribute__((ext_vector_type(8))) __bf16 bf16x8;
typedef __attribute__((ext_vector_type(4))) float f32x4;

// tanh(x) = 1 - 2/(exp(2x)+1); exp2-based, v_exp+v_rcp. Handles +-inf naturally.
static __device__ __forceinline__ float tanh_fast(float x){
    float t = __builtin_amdgcn_exp2f(x * 2.8853900817779268f);
    return 1.0f - 2.0f * __builtin_amdgcn_rcpf(t + 1.0f);
}
static __device__ __forceinline__ float sigmoid_fast(float x){
    return __builtin_amdgcn_rcpf(1.0f + __builtin_amdgcn_exp2f(-1.4426950408889634f * x));
}

// ---------------- kernel 1: init accumulators + min/max of timepoints ----------------
__global__ void k_init(const int* __restrict__ tp, float* wsf){
    int* wsi = (int*)wsf;
    __shared__ int smin[256], smax[256];
    int tid = threadIdx.x;
    int mn = 2147483647, mx = -2147483647-1;
    for (int i = tid; i < B*T; i += 256){ int v = tp[i]; mn = min(mn,v); mx = max(mx,v); }
    smin[tid]=mn; smax[tid]=mx; __syncthreads();
    for (int s=128; s>0; s>>=1){
        if (tid<s){ smin[tid]=min(smin[tid],smin[tid+s]); smax[tid]=max(smax[tid],smax[tid+s]); }
        __syncthreads();
    }
    if (tid==0){
        wsi[WS_MIN]=smin[0]; wsi[WS_MAX]=smax[0];
        wsf[WS_KL]=0.f; wsf[WS_RE]=0.f; wsf[WS_NO]=0.f;
    }
}

// ---------------- kernel 2: build integration grid (f64 to match numpy) ----------------
__global__ void k_grid(float* wsf){
    int* wsi=(int*)wsf;
    float t0f = (float)wsi[WS_MIN] / FSCALE;
    float t1f = (float)wsi[WS_MAX] / FSCALE;
    double t0d = (double)t0f, t1d = (double)t1f;
    int nit = (int)ceil((t1d-t0d)/0.05 + 1.0);
    if (nit < 1) nit = 1;
    if (nit > MAXGRID) nit = MAXGRID;
    if (threadIdx.x==0) wsi[WS_NIT] = nit;
    int k = threadIdx.x;
    if (k < nit){
        double g = (double)k * 0.05 + t0d;
        if (k == nit-1 && g > t1d) g = t1d;
        wsf[WS_GRID + k] = (float)g;
    }
}

// ---------------- kernel 3: GRU encoder via MFMA (16 rows/block, 8 waves) ----------------
// Fused-gate trick: r,z gates use sigmoid(ir+hr) -> one GEMM over stacked [x,h].
// dt (col 64, magnitude ~2000) excluded from bf16 GEMM; added as exact f32 rank-1 term.
// A frag: lane holds A[lane&15][8*(lane>>4)+e]; C/D: C[4*(lane>>4)+j][lane&15].
__global__ __launch_bounds__(512) void k_gru(
    const float* __restrict__ obs, const float* __restrict__ eps,
    const float* __restrict__ Wih, const float* __restrict__ Whh,
    const float* __restrict__ bih, const float* __restrict__ bhh,
    const float* __restrict__ Wmu, const float* __restrict__ bmu,
    const float* __restrict__ Wlv, const float* __restrict__ blv,
    const int* __restrict__ maskI, const int* __restrict__ tp,
    float* wsf)
{
    const int b0 = blockIdx.x * 16;
    const int tid = threadIdx.x;
    const int w = tid >> 6, lane = tid & 63;
    const int g = lane >> 4, c = lane & 15;
    const int xr = tid >> 5, xl = tid & 31;   // x-loader: row, lab index

    // k-layout of xh: [0,32): obs*mask, [32,64): mask, [64,96): zero (dt excluded), [96,224): h
    __shared__ __align__(16) __bf16 xh[16][232];   // row stride 464B (29*16)
    __shared__ int   tps[16][64];
    __shared__ float dts[16];
    __shared__ float lvs[16][64];
    __shared__ float red[8];

    // ---- load tp block, zero xh ----
    ((int2*)tps)[tid] = ((const int2*)(tp + (size_t)b0*T))[tid];
    {
        unsigned* xz = (unsigned*)&xh[0][0];
        #pragma unroll
        for (int i=0;i<1856;i+=512) xz[i+tid] = 0u;
    }

    // ---- weight fragments (bf16, VGPR-resident) ----
    // fused k-tiles q=0..5 -> kt = q<2? q : q+1  (skip zero tile kt=2)
    bf16x8 wr[6], wz[6], wi[2], wh[4];
    #pragma unroll
    for (int q=0;q<6;++q){
        int kt = q<2 ? q : q+1;
        #pragma unroll
        for (int e=0;e<8;++e){
            int k = kt*32 + g*8 + e;
            float vr, vz;
            if (k < 64){ vr = Wih[k*G3 + 16*w+c];      vz = Wih[k*G3 + 128+16*w+c]; }
            else       { vr = Whh[(k-96)*G3 + 16*w+c]; vz = Whh[(k-96)*G3 + 128+16*w+c]; }
            wr[q][e] = (__bf16)vr; wz[q][e] = (__bf16)vz;
        }
    }
    #pragma unroll
    for (int q=0;q<2;++q)
        #pragma unroll
        for (int e=0;e<8;++e)
            wi[q][e] = (__bf16)Wih[(q*32+g*8+e)*G3 + 256+16*w+c];
    #pragma unroll
    for (int q=0;q<4;++q)
        #pragma unroll
        for (int e=0;e<8;++e)
            wh[q][e] = (__bf16)Whh[(q*32+g*8+e)*G3 + 256+16*w+c];
    const float wdr = Wih[64*G3 + 16*w+c];
    const float wdz = Wih[64*G3 + 128+16*w+c];
    const float wdn = Wih[64*G3 + 256+16*w+c];
    const float rb  = bih[16*w+c]     + bhh[16*w+c];
    const float zb  = bih[128+16*w+c] + bhh[128+16*w+c];
    const float inb = bih[256+16*w+c];
    const float hnb = bhh[256+16*w+c];

    __syncthreads();  // tps + zeroed xh visible

    // ---- initial x (t = 63) ----
    {
        float mv = (float)maskI[((size_t)(b0+xr)*T + 63)*NL + xl];
        float ov = obs[((size_t)(b0+xr)*T + 63)*NL + xl];
        xh[xr][xl]    = (__bf16)(ov*mv);
        xh[xr][32+xl] = (__bf16)mv;
        if (xl==0) dts[xr] = (float)(tps[xr][63]-tps[xr][62]);
    }

    float hold[4] = {0.f,0.f,0.f,0.f};   // h rows 4g+j, col 16w+c

    for (int s=0;s<T;++s){
        const int t = T-1-s;
        __syncthreads();   // xh, dts ready
        // A-fragments (shared across all 4 gate GEMMs)
        bf16x8 A0 = *(const bf16x8*)&xh[c][0*32 + g*8];
        bf16x8 A1 = *(const bf16x8*)&xh[c][1*32 + g*8];
        bf16x8 A2 = *(const bf16x8*)&xh[c][3*32 + g*8];
        bf16x8 A3 = *(const bf16x8*)&xh[c][4*32 + g*8];
        bf16x8 A4 = *(const bf16x8*)&xh[c][5*32 + g*8];
        bf16x8 A5 = *(const bf16x8*)&xh[c][6*32 + g*8];
        const float dt0=dts[4*g], dt1=dts[4*g+1], dt2=dts[4*g+2], dt3=dts[4*g+3];
        // prefetch next x under the MFMA phase
        float ov=0.f, mvn=0.f; const int tn = t-1;
        if (s < T-1){
            mvn = (float)maskI[((size_t)(b0+xr)*T + tn)*NL + xl];
            ov  = obs[((size_t)(b0+xr)*T + tn)*NL + xl];
        }
        // 18 MFMAs: 4 independent accumulation chains
        f32x4 racc={0,0,0,0}, zacc={0,0,0,0}, inacc={0,0,0,0}, hnacc={0,0,0,0};
        racc  = __builtin_amdgcn_mfma_f32_16x16x32_bf16(A0, wr[0], racc, 0,0,0);
        zacc  = __builtin_amdgcn_mfma_f32_16x16x32_bf16(A0, wz[0], zacc, 0,0,0);
        inacc = __builtin_amdgcn_mfma_f32_16x16x32_bf16(A0, wi[0], inacc,0,0,0);
        hnacc = __builtin_amdgcn_mfma_f32_16x16x32_bf16(A2, wh[0], hnacc,0,0,0);
        racc  = __builtin_amdgcn_mfma_f32_16x16x32_bf16(A1, wr[1], racc, 0,0,0);
        zacc  = __builtin_amdgcn_mfma_f32_16x16x32_bf16(A1, wz[1], zacc, 0,0,0);
        inacc = __builtin_amdgcn_mfma_f32_16x16x32_bf16(A1, wi[1], inacc,0,0,0);
        hnacc = __builtin_amdgcn_mfma_f32_16x16x32_bf16(A3, wh[1], hnacc,0,0,0);
        racc  = __builtin_amdgcn_mfma_f32_16x16x32_bf16(A2, wr[2], racc, 0,0,0);
        zacc  = __builtin_amdgcn_mfma_f32_16x16x32_bf16(A2, wz[2], zacc, 0,0,0);
        hnacc = __builtin_amdgcn_mfma_f32_16x16x32_bf16(A4, wh[2], hnacc,0,0,0);
        racc  = __builtin_amdgcn_mfma_f32_16x16x32_bf16(A3, wr[3], racc, 0,0,0);
        zacc  = __builtin_amdgcn_mfma_f32_16x16x32_bf16(A3, wz[3], zacc, 0,0,0);
        hnacc = __builtin_amdgcn_mfma_f32_16x16x32_bf16(A5, wh[3], hnacc,0,0,0);
        racc  = __builtin_amdgcn_mfma_f32_16x16x32_bf16(A4, wr[4], racc, 0,0,0);
        zacc  = __builtin_amdgcn_mfma_f32_16x16x32_bf16(A4, wz[4], zacc, 0,0,0);
        racc  = __builtin_amdgcn_mfma_f32_16x16x32_bf16(A5, wr[5], racc, 0,0,0);
        zacc  = __builtin_amdgcn_mfma_f32_16x16x32_bf16(A5, wz[5], zacc, 0,0,0);
        // gates + h update (dt rank-1 term in exact f32)
        float hnew[4]; const float dtv[4] = {dt0,dt1,dt2,dt3};
        #pragma unroll
        for (int j=0;j<4;++j){
            float dv = dtv[j];
            float r  = sigmoid_fast(racc[j] + rb + dv*wdr);
            float zg = sigmoid_fast(zacc[j] + zb + dv*wdz);
            float n  = tanh_fast(inacc[j] + inb + dv*wdn + r*(hnacc[j] + hnb));
            float hv = (1.f - zg)*n + zg*hold[j];
            hold[j] = hv; hnew[j] = hv;
        }
        __syncthreads();   // all A-frag reads done
        #pragma unroll
        for (int j=0;j<4;++j) xh[4*g+j][96+16*w+c] = (__bf16)hnew[j];
        if (s < T-1){
            xh[xr][xl]    = (__bf16)(ov*mvn);
            xh[xr][32+xl] = (__bf16)mvn;
            if (xl==0) dts[xr] = (tn>0) ? (float)(tps[xr][tn]-tps[xr][tn-1]) : 0.f;
        }
    }
    __syncthreads();   // final h in xh

    // ---- mu (waves 0-3) / logvar (waves 4-7) via MFMA, then z0 + KL ----
    const int col4 = 16*(w&3)+c;
    bf16x8 Ah0 = *(const bf16x8*)&xh[c][96+0*32+g*8];
    bf16x8 Ah1 = *(const bf16x8*)&xh[c][96+1*32+g*8];
    bf16x8 Ah2 = *(const bf16x8*)&xh[c][96+2*32+g*8];
    bf16x8 Ah3 = *(const bf16x8*)&xh[c][96+3*32+g*8];
    const float* Wm = (w<4)? Wmu : Wlv;
    f32x4 acc={0,0,0,0};
    {
        bf16x8 bf0,bf1,bf2,bf3;
        #pragma unroll
        for (int e=0;e<8;++e){
            bf0[e] = (__bf16)Wm[(0*32+g*8+e)*LAT + col4];
            bf1[e] = (__bf16)Wm[(1*32+g*8+e)*LAT + col4];
            bf2[e] = (__bf16)Wm[(2*32+g*8+e)*LAT + col4];
            bf3[e] = (__bf16)Wm[(3*32+g*8+e)*LAT + col4];
        }
        acc = __builtin_amdgcn_mfma_f32_16x16x32_bf16(Ah0, bf0, acc, 0,0,0);
        acc = __builtin_amdgcn_mfma_f32_16x16x32_bf16(Ah1, bf1, acc, 0,0,0);
        acc = __builtin_amdgcn_mfma_f32_16x16x32_bf16(Ah2, bf2, acc, 0,0,0);
        acc = __builtin_amdgcn_mfma_f32_16x16x32_bf16(Ah3, bf3, acc, 0,0,0);
    }
    const float mbias = (w<4)? bmu[col4] : blv[col4];
    if (w>=4){
        #pragma unroll
        for (int j=0;j<4;++j) lvs[4*g+j][col4] = acc[j] + mbias;
    }
    __syncthreads();
    if (w<4){
        float kl = 0.f;
        #pragma unroll
        for (int j=0;j<4;++j){
            float mu = acc[j] + mbias;
            float lv = lvs[4*g+j][col4];
            int row = b0 + 4*g + j;
            float z0 = mu + eps[(size_t)row*LAT + col4]*expf(0.5f*lv);
            wsf[WS_Z0 + (size_t)row*LAT + col4] = z0;
            wsf[WS_YS + (size_t)row*LAT + col4] = z0;
            kl += 1.f + lv - mu*mu - expf(lv);
        }
        #pragma unroll
        for (int off=32; off>0; off>>=1) kl += __shfl_xor(kl, off);
        if (lane==0) red[w] = kl;
    }
    __syncthreads();
    if (tid==0) atomicAdd(&wsf[WS_KL], red[0]+red[1]+red[2]+red[3]);
}

// ---------------- kernel 4: RK4 ODE via MFMA, 16 rows/block, 8 waves ----------------
__global__ __launch_bounds__(512) void k_ode(
    const float* __restrict__ W1, const float* __restrict__ b1,
    const float* __restrict__ W2, const float* __restrict__ b2,
    const float* __restrict__ W3, const float* __restrict__ b3,
    float* wsf)
{
    const int b0 = blockIdx.x * R_ODE;
    const int tid = threadIdx.x;
    const int w = tid >> 6, lane = tid & 63;
    const int g = lane >> 4, c = lane & 15;
    const int w3c = 16*(w&3) + c;     // stage-3 column for waves 0-3
    const int* wsi = (const int*)wsf;
    const int nit = wsi[WS_NIT];

    __shared__ __align__(16) __bf16 zin[16][72];   // row stride 144B
    __shared__ __align__(16) __bf16 h1s[16][136];  // row stride 272B
    __shared__ __align__(16) __bf16 h2s[16][136];
    __shared__ float gls[MAXGRID];

    bf16x8 w1f[2], w2f[4], w3f[4];
    #pragma unroll
    for (int q=0;q<2;++q)
        #pragma unroll
        for (int e=0;e<8;++e)
            w1f[q][e] = (__bf16)W1[(q*32+g*8+e)*HID + 16*w+c];
    #pragma unroll
    for (int q=0;q<4;++q)
        #pragma unroll
        for (int e=0;e<8;++e)
            w2f[q][e] = (__bf16)W2[(q*32+g*8+e)*HID + 16*w+c];
    #pragma unroll
    for (int q=0;q<4;++q)
        #pragma unroll
        for (int e=0;e<8;++e)
            w3f[q][e] = (__bf16)W3[(q*32+g*8+e)*LAT + w3c];
    const float b1v = b1[16*w+c];
    const float b2v = b2[16*w+c];
    const float b3v = b3[w3c];

    float y[4], facc[4];
    if (w < 4){
        #pragma unroll
        for (int j=0;j<4;++j){
            y[j] = wsf[WS_Z0 + (size_t)(b0 + 4*g + j)*LAT + w3c];
            zin[4*g+j][w3c] = (__bf16)y[j];
            facc[j] = 0.f;
        }
    }
    for (int kk=tid; kk<MAXGRID; kk+=512) gls[kk] = wsf[WS_GRID+kk];
    __syncthreads();

    for (int i=0; i<nit-1; ++i){
        float h = gls[i+1]-gls[i];
        #pragma unroll
        for (int sub=0; sub<4; ++sub){
            f32x4 a1 = {0.f,0.f,0.f,0.f};
            {
                bf16x8 az0 = *(const bf16x8*)&zin[c][g*8];
                bf16x8 az1 = *(const bf16x8*)&zin[c][32+g*8];
                a1 = __builtin_amdgcn_mfma_f32_16x16x32_bf16(az0, w1f[0], a1, 0,0,0);
                a1 = __builtin_amdgcn_mfma_f32_16x16x32_bf16(az1, w1f[1], a1, 0,0,0);
            }
            #pragma unroll
            for (int j=0;j<4;++j)
                h1s[4*g+j][16*w+c] = (__bf16)tanh_fast(a1[j] + b1v);
            __syncthreads();
            f32x4 c2a = {0.f,0.f,0.f,0.f}, c2b = {0.f,0.f,0.f,0.f};
            {
                bf16x8 aq0 = *(const bf16x8*)&h1s[c][g*8];
                bf16x8 aq1 = *(const bf16x8*)&h1s[c][32+g*8];
                bf16x8 aq2 = *(const bf16x8*)&h1s[c][64+g*8];
                bf16x8 aq3 = *(const bf16x8*)&h1s[c][96+g*8];
                c2a = __builtin_amdgcn_mfma_f32_16x16x32_bf16(aq0, w2f[0], c2a, 0,0,0);
                c2b = __builtin_amdgcn_mfma_f32_16x16x32_bf16(aq2, w2f[2], c2b, 0,0,0);
                c2a = __builtin_amdgcn_mfma_f32_16x16x32_bf16(aq1, w2f[1], c2a, 0,0,0);
                c2b = __builtin_amdgcn_mfma_f32_16x16x32_bf16(aq3, w2f[3], c2b, 0,0,0);
            }
            #pragma unroll
            for (int j=0;j<4;++j)
                h2s[4*g+j][16*w+c] = (__bf16)tanh_fast((c2a[j]+c2b[j]) + b2v);
            __syncthreads();
            if (w < 4){
                f32x4 c3a = {0.f,0.f,0.f,0.f}, c3b = {0.f,0.f,0.f,0.f};
                bf16x8 aq0 = *(const bf16x8*)&h2s[c][g*8];
                bf16x8 aq1 = *(const bf16x8*)&h2s[c][32+g*8];
                bf16x8 aq2 = *(const bf16x8*)&h2s[c][64+g*8];
                bf16x8 aq3 = *(const bf16x8*)&h2s[c][96+g*8];
                c3a = __builtin_amdgcn_mfma_f32_16x16x32_bf16(aq0, w3f[0], c3a, 0,0,0);
                c3b = __builtin_amdgcn_mfma_f32_16x16x32_bf16(aq2, w3f[2], c3b, 0,0,0);
                c3a = __builtin_amdgcn_mfma_f32_16x16x32_bf16(aq1, w3f[1], c3a, 0,0,0);
                c3b = __builtin_amdgcn_mfma_f32_16x16x32_bf16(aq3, w3f[3], c3b, 0,0,0);
                #pragma unroll
                for (int j=0;j<4;++j){
                    float f = (c3a[j]+c3b[j]) + b3v;
                    float zn;
                    if (sub==0){ facc[j] = f;         zn = fmaf(0.5f*h, f, y[j]); }
                    else if (sub==1){ facc[j] += 2.f*f; zn = fmaf(0.5f*h, f, y[j]); }
                    else if (sub==2){ facc[j] += 2.f*f; zn = fmaf(h, f, y[j]); }
                    else {
                        facc[j] += f;
                        y[j] = fmaf(h*(1.0f/6.0f), facc[j], y[j]);
                        zn = y[j];
                        wsf[WS_YS + ((size_t)(i+1)*B + (b0+4*g+j))*LAT + w3c] = y[j];
                    }
                    zin[4*g+j][w3c] = (__bf16)zn;
                }
            }
            __syncthreads();
        }
    }
}

// ---------------- kernel 5: recon via MFMA (1 block per b, 8 waves) ----------------
__global__ __launch_bounds__(512) void k_recon(
    const float* __restrict__ obs, const int* __restrict__ maskI,
    const int* __restrict__ tp, const int* __restrict__ seq,
    const float* __restrict__ Wo1, const float* __restrict__ bo1,
    const float* __restrict__ Wo2, const float* __restrict__ bo2,
    float* wsf)
{
    const int b = blockIdx.x, tid = threadIdx.x;
    const int w = tid >> 6, lane = tid & 63;
    const int g = lane >> 4, c = lane & 15;
    __shared__ __align__(16) __bf16 zbt[64][72];
    __shared__ __align__(16) __bf16 hb[64][136];
    __shared__ float gls[MAXGRID];
    __shared__ float red[16];
    const int* wsi=(const int*)wsf;
    const int nit = wsi[WS_NIT];
    for (int i=tid;i<MAXGRID;i+=512) gls[i]=wsf[WS_GRID+i];

    bf16x8 wo1f[2], wo2f[4];
    #pragma unroll
    for (int q=0;q<2;++q)
        #pragma unroll
        for (int e=0;e<8;++e)
            wo1f[q][e] = (__bf16)Wo1[(q*32+g*8+e)*HID + 16*w+c];
    {
        int n = w & 1;
        #pragma unroll
        for (int q=0;q<4;++q)
            #pragma unroll
            for (int e=0;e<8;++e)
                wo2f[q][e] = (__bf16)Wo2[(q*32+g*8+e)*NL + 16*n+c];
    }
    const float bo1v = bo1[16*w+c];
    const float bo2v = bo2[16*(w&1)+c];
    const int sl = seq[b];
    __syncthreads();

    {
        int t = tid >> 3, seg = tid & 7;
        float tq = (float)tp[b*T+t] / FSCALE;
        int lo=0, hi=nit;
        while (lo<hi){ int mid=(lo+hi)>>1; if (gls[mid]<=tq) lo=mid+1; else hi=mid; }
        int k = lo-1; if (k<0) k=0; if (nit>=2 && k>nit-2) k=nit-2; if (nit<2) k=0;
        float wq=0.f;
        if (nit>=2){ float tl=gls[k], tr=gls[k+1]; float den=(tr-tl==0.f)?1.f:(tr-tl); wq=(tq-tl)/den; }
        size_t o0 = (size_t)WS_YS + ((size_t)k*B + b)*LAT + seg*8;
        float4 za0 = *(const float4*)&wsf[o0];
        float4 za1 = *(const float4*)&wsf[o0+4];
        float4 zb0, zb1;
        if (nit>=2){
            zb0 = *(const float4*)&wsf[o0 + (size_t)B*LAT];
            zb1 = *(const float4*)&wsf[o0 + (size_t)B*LAT + 4];
        } else { zb0 = za0; zb1 = za1; }
        __bf16* dst = &zbt[t][seg*8];
        dst[0] = (__bf16)(za0.x*(1.f-wq)+zb0.x*wq);
        dst[1] = (__bf16)(za0.y*(1.f-wq)+zb0.y*wq);
        dst[2] = (__bf16)(za0.z*(1.f-wq)+zb0.z*wq);
        dst[3] = (__bf16)(za0.w*(1.f-wq)+zb0.w*wq);
        dst[4] = (__bf16)(za1.x*(1.f-wq)+zb1.x*wq);
        dst[5] = (__bf16)(za1.y*(1.f-wq)+zb1.y*wq);
        dst[6] = (__bf16)(za1.z*(1.f-wq)+zb1.z*wq);
        dst[7] = (__bf16)(za1.w*(1.f-wq)+zb1.w*wq);
    }
    __syncthreads();

    #pragma unroll
    for (int m=0;m<4;++m){
        f32x4 acc = {0.f,0.f,0.f,0.f};
        bf16x8 a0 = *(const bf16x8*)&zbt[16*m+c][g*8];
        bf16x8 a1 = *(const bf16x8*)&zbt[16*m+c][32+g*8];
        acc = __builtin_amdgcn_mfma_f32_16x16x32_bf16(a0, wo1f[0], acc, 0,0,0);
        acc = __builtin_amdgcn_mfma_f32_16x16x32_bf16(a1, wo1f[1], acc, 0,0,0);
        #pragma unroll
        for (int j=0;j<4;++j)
            hb[16*m+4*g+j][16*w+c] = (__bf16)fmaxf(acc[j] + bo1v, 0.f);
    }
    __syncthreads();

    float esum = 0.f, ncnt = 0.f;
    {
        int m = w >> 1, n = w & 1;
        f32x4 ca = {0.f,0.f,0.f,0.f}, cb = {0.f,0.f,0.f,0.f};
        bf16x8 a0 = *(const bf16x8*)&hb[16*m+c][g*8];
        bf16x8 a1 = *(const bf16x8*)&hb[16*m+c][32+g*8];
        bf16x8 a2 = *(const bf16x8*)&hb[16*m+c][64+g*8];
        bf16x8 a3 = *(const bf16x8*)&hb[16*m+c][96+g*8];
        ca = __builtin_amdgcn_mfma_f32_16x16x32_bf16(a0, wo2f[0], ca, 0,0,0);
        cb = __builtin_amdgcn_mfma_f32_16x16x32_bf16(a2, wo2f[2], cb, 0,0,0);
        ca = __builtin_amdgcn_mfma_f32_16x16x32_bf16(a1, wo2f[1], ca, 0,0,0);
        cb = __builtin_amdgcn_mfma_f32_16x16x32_bf16(a3, wo2f[3], cb, 0,0,0);
        #pragma unroll
        for (int j=0;j<4;++j){
            int t = 16*m + 4*g + j;
            int col = 16*n + c;
            float xh2 = (ca[j]+cb[j]) + bo2v;
            float mv = (float)maskI[(b*T+t)*NL+col] * ((t<sl)?1.f:0.f);
            float d = xh2 - obs[(b*T+t)*NL+col];
            esum = fmaf(mv*d, d, esum);
            ncnt += mv;
        }
    }
    #pragma unroll
    for (int off=32; off>0; off>>=1){
        esum += __shfl_xor(esum, off);
        ncnt += __shfl_xor(ncnt, off);
    }
    if (lane==0){ red[w] = esum; red[8+w] = ncnt; }
    __syncthreads();
    if (tid==0){
        float s=0.f, nn=0.f;
        #pragma unroll
        for (int i=0;i<8;++i){ s += red[i]; nn += red[8+i]; }
        atomicAdd(&wsf[WS_RE], s);
        atomicAdd(&wsf[WS_NO], nn);
    }
}

// ---------------- kernel 6: z_eval + survival head ----------------
__global__ __launch_bounds__(128) void k_surv(
    const float* __restrict__ age, const int* __restrict__ tp, const int* __restrict__ seq,
    const float* __restrict__ Ws1, const float* __restrict__ bs1,
    const float* __restrict__ Ws2, const float* __restrict__ bs2,
    float* wsf, float* out)
{
    int b=blockIdx.x, tid=threadIdx.x;
    __shared__ float gls[MAXGRID];
    __shared__ float ze[64];
    __shared__ float pred[4];
    const int* wsi=(const int*)wsf; int nit=wsi[WS_NIT];
    for (int i=tid;i<MAXGRID;i+=128) gls[i]=wsf[WS_GRID+i];
    __syncthreads();
    int sl = seq[b];
    float tq = (float)tp[b*T + sl-1] / FSCALE;
    int lo=0,hi=nit;
    while(lo<hi){int mid=(lo+hi)>>1; if (gls[mid]<=tq) lo=mid+1; else hi=mid;}
    int k=lo-1; if(k<0)k=0; if(nit>=2 && k>nit-2)k=nit-2; if (nit<2) k=0;
    float w=0.f;
    if (nit>=2){ float tl=gls[k],tr=gls[k+1]; float den=(tr-tl==0.f)?1.f:(tr-tl); w=(tq-tl)/den; }
    if (tid<LAT){
        size_t o0 = (size_t)WS_YS + ((size_t)k*B+b)*LAT+tid;
        float zl = wsf[o0]*(1.f-w) + ((nit>=2)? wsf[o0+(size_t)B*LAT]*w : 0.f);
        ze[tid]=zl;
        out[1026 + b*LAT + tid] = zl;
    }
    __syncthreads();
    float hj = bs1[tid];
    #pragma unroll 8
    for (int l=0;l<LAT;++l) hj = fmaf(ze[l], Ws1[l*HID+tid], hj);
    hj = fmaf(age[b], Ws1[LAT*HID+tid], hj);
    hj = fmaxf(hj,0.f);
    float p0 = hj*Ws2[tid*2+0], p1 = hj*Ws2[tid*2+1];
    #pragma unroll
    for (int off=32;off>0;off>>=1){ p0 += __shfl_down(p0,off); p1 += __shfl_down(p1,off); }
    int wv = tid>>6;
    if ((tid&63)==0){ pred[wv*2]=p0; pred[wv*2+1]=p1; }
    __syncthreads();
    if (tid==0){
        out[b*2+0] = bs2[0] + pred[0]+pred[2];
        out[b*2+1] = bs2[1] + pred[1]+pred[3];
    }
}

// ---------------- kernel 7: finalize scalars ----------------
__global__ void k_fin(float* wsf, float* out){
    float n = wsf[WS_NO];
    out[1024] = (n>0.f) ? (wsf[WS_RE]/fmaxf(n,1.f)) : 0.f;
    out[1025] = -0.5f * (wsf[WS_KL] / (float)B);
}

extern "C" void kernel_launch(void* const* d_in, const int* in_sizes, int n_in,
                              void* d_out, int out_size, void* d_ws, size_t ws_size,
                              hipStream_t stream) {
    const float* obs   = (const float*)d_in[0];
    const float* age   = (const float*)d_in[1];
    const float* eps   = (const float*)d_in[2];
    const float* Wih   = (const float*)d_in[3];
    const float* Whh   = (const float*)d_in[4];
    const float* bih   = (const float*)d_in[5];
    const float* bhh   = (const float*)d_in[6];
    const float* Wmu   = (const float*)d_in[7];
    const float* bmu   = (const float*)d_in[8];
    const float* Wlv   = (const float*)d_in[9];
    const float* blv   = (const float*)d_in[10];
    const float* W1    = (const float*)d_in[11];
    const float* b1    = (const float*)d_in[12];
    const float* W2    = (const float*)d_in[13];
    const float* b2    = (const float*)d_in[14];
    const float* W3    = (const float*)d_in[15];
    const float* b3    = (const float*)d_in[16];
    const float* Wo1   = (const float*)d_in[17];
    const float* bo1   = (const float*)d_in[18];
    const float* Wo2   = (const float*)d_in[19];
    const float* bo2   = (const float*)d_in[20];
    const float* Ws1   = (const float*)d_in[21];
    const float* bs1   = (const float*)d_in[22];
    const float* Ws2   = (const float*)d_in[23];
    const float* bs2   = (const float*)d_in[24];
    const int*   maskI = (const int*)d_in[25];
    const int*   tp    = (const int*)d_in[26];
    const int*   seq   = (const int*)d_in[27];
    float* wsf = (float*)d_ws;
    float* out = (float*)d_out;

    k_init<<<1, 256, 0, stream>>>(tp, wsf);
    k_grid<<<1, 128, 0, stream>>>(wsf);
    k_gru<<<B/16, 512, 0, stream>>>(obs, eps, Wih, Whh, bih, bhh, Wmu, bmu, Wlv, blv,
                                    maskI, tp, wsf);
    k_ode<<<B/R_ODE, 512, 0, stream>>>(W1, b1, W2, b2, W3, b3, wsf);
    k_recon<<<B, 512, 0, stream>>>(obs, maskI, tp, seq, Wo1, bo1, Wo2, bo2, wsf);
    k_surv<<<B, 128, 0, stream>>>(age, tp, seq, Ws1, bs1, Ws2, bs2, wsf, out);
    k_fin<<<1, 1, 0, stream>>>(wsf, out);
}